// Round 1
// baseline (804.374 us; speedup 1.0000x reference)
//
#include <hip/hip_runtime.h>
#include <math.h>

#define NB 2
#define NC 96
#define ND 8
#define NHH 64
#define NWW 64
#define NN 32768          // ND*NHH*NWW
#define NTOK 8
#define NHEADS 6
#define GSZ 128
#define NGRP 256          // NN/GSZ
#define NMLP 192

typedef float4 f4;

__device__ __forceinline__ float gelu_f(float x) {
    return 0.5f * x * (1.0f + erff(x * 0.70710678118654752440f));
}

// ---------------------------------------------------------------------------
// Precompute: normalized means, gdot/bdot (for fused cluster scores),
// kg/vg (global attention K/V from cluster means), wpc = Wproj @ Wconv
// ---------------------------------------------------------------------------
__global__ void __launch_bounds__(256) k_precompute(
    const float* __restrict__ means, const float* __restrict__ g1, const float* __restrict__ b1v,
    const float* __restrict__ Wkg, const float* __restrict__ Wvg,
    const float* __restrict__ Wproj, const float* __restrict__ Wconv,
    float* __restrict__ mnn, float* __restrict__ gdot, float* __restrict__ bdot,
    float* __restrict__ kg, float* __restrict__ vg, float* __restrict__ wpc) {
    int tid = threadIdx.x;
    if (tid < NTOK) {
        float ss = 0.f;
        for (int c = 0; c < NC; ++c) { float v = means[tid*NC+c]; ss += v*v; }
        float nrm = fmaxf(sqrtf(ss), 1e-12f);
        float inv = 1.0f / nrm;
        float gd = 0.f, bd = 0.f;
        for (int c = 0; c < NC; ++c) {
            float v = means[tid*NC+c] * inv;
            mnn[tid*NC+c] = v;
            gd += g1[c]*v; bd += b1v[c]*v;
        }
        gdot[tid] = gd; bdot[tid] = bd;
    }
    // kg/vg: layout [h][t][e], e<16
    for (int i = tid; i < NHEADS*NTOK*16; i += 256) {
        int h = i / (NTOK*16); int r = i % (NTOK*16); int t = r / 16; int e = r % 16;
        float sk = 0.f, sv = 0.f;
        for (int c = 0; c < NC; ++c) {
            float mv = means[t*NC+c];
            sk += mv * Wkg[c*NC + h*16+e];
            sv += mv * Wvg[c*NC + h*16+e];
        }
        kg[i] = sk; vg[i] = sv;
    }
    // wpc = Wproj @ Wconv (96x96)
    for (int i = tid; i < NC*NC; i += 256) {
        int r = i / NC, c = i % NC;
        float s = 0.f;
        for (int k = 0; k < NC; ++k) s += Wproj[r*NC+k]*Wconv[k*NC+c];
        wpc[i] = s;
    }
}

// ---------------------------------------------------------------------------
// LN1 (reads x in (b,c,n), writes xn in (b,n,c)) fused with cluster argmax.
// score_t = rstd*(sum_c a_c*g_c*mnn_t_c - mean*gdot_t) + bdot_t  (argmax-equiv)
// ---------------------------------------------------------------------------
__global__ void __launch_bounds__(256) k_ln1(
    const float* __restrict__ x, const float* __restrict__ g1, const float* __restrict__ b1v,
    const float* __restrict__ mnn, const float* __restrict__ gdot, const float* __restrict__ bdot,
    float* __restrict__ xn, int* __restrict__ belong) {
    __shared__ __align__(16) float xt[NC][68];
    __shared__ float meanl[64], rstdl[64];
    __shared__ float gl[NC], bl[NC], gdl[NTOK], bdl[NTOK];
    int b = blockIdx.y; int n0 = blockIdx.x * 64;
    int tid = threadIdx.x;
    if (tid < NC) { gl[tid] = g1[tid]; bl[tid] = b1v[tid]; }
    if (tid >= NC && tid < NC+NTOK) { gdl[tid-NC] = gdot[tid-NC]; bdl[tid-NC] = bdot[tid-NC]; }
    for (int i = tid; i < NC*64; i += 256) {
        int c = i >> 6, n = i & 63;
        xt[c][n] = x[((size_t)b*NC + c)*NN + n0 + n];
    }
    __syncthreads();
    int lane = tid & 63, w = tid >> 6;
    float ga = gl[lane];
    float gb = (lane < 32) ? gl[64+lane] : 0.f;
    float ma[NTOK], mb[NTOK];
#pragma unroll
    for (int t = 0; t < NTOK; ++t) {
        ma[t] = mnn[t*NC + lane];
        mb[t] = (lane < 32) ? mnn[t*NC + 64 + lane] : 0.f;
    }
    for (int tk = 0; tk < 16; ++tk) {
        int tok = w*16 + tk;
        float a  = xt[lane][tok];
        float bb = (lane < 32) ? xt[64+lane][tok] : 0.f;
        float red[10];
        red[0] = a + bb;
        red[1] = a*a + bb*bb;
        float ag = a*ga, bg = bb*gb;
#pragma unroll
        for (int t = 0; t < NTOK; ++t) red[2+t] = ag*ma[t] + bg*mb[t];
#pragma unroll
        for (int off = 32; off > 0; off >>= 1) {
#pragma unroll
            for (int r = 0; r < 10; ++r) red[r] += __shfl_xor(red[r], off);
        }
        if (lane == 0) {
            float mean = red[0] * (1.0f/NC);
            float var  = red[1] * (1.0f/NC) - mean*mean;
            float rstd = rsqrtf(var + 1e-5f);
            meanl[tok] = mean; rstdl[tok] = rstd;
            int best = 0; float bestv = -1e30f;
#pragma unroll
            for (int t = 0; t < NTOK; ++t) {
                float sc = rstd*(red[2+t] - mean*gdl[t]) + bdl[t];
                if (sc > bestv) { bestv = sc; best = t; }
            }
            belong[b*NN + n0 + tok] = best;
        }
    }
    __syncthreads();
    for (int i = tid; i < 64*NC; i += 256) {
        int n = i / NC, c = i % NC;
        float v = (xt[c][n] - meanl[n]) * rstdl[n] * gl[c] + bl[c];
        xn[((size_t)b*NN + n0 + n)*NC + c] = v;
    }
}

// ---------------------------------------------------------------------------
// Stable counting sort of `belong` (values 0..7): hist -> scan -> scatter
// ---------------------------------------------------------------------------
__global__ void __launch_bounds__(256) k_hist(const int* __restrict__ belong, int* __restrict__ hist) {
    int b = blockIdx.y, ch = blockIdx.x, tid = threadIdx.x;
    __shared__ int wc[4][NTOK];
    int myt = belong[b*NN + ch*256 + tid];
    int w = tid >> 6, lane = tid & 63;
#pragma unroll
    for (int t = 0; t < NTOK; ++t) {
        unsigned long long m = __ballot(myt == t);
        if (lane == 0) wc[w][t] = __popcll(m);
    }
    __syncthreads();
    if (tid < NTOK) hist[(b*128 + ch)*NTOK + tid] = wc[0][tid]+wc[1][tid]+wc[2][tid]+wc[3][tid];
}

__global__ void __launch_bounds__(256) k_scan(const int* __restrict__ hist, int* __restrict__ base) {
    int b = blockIdx.x, tid = threadIdx.x;
    __shared__ int A[NTOK][128], Bf[NTOK][128], orig[NTOK][128];
    __shared__ int cb[NTOK];
    for (int i = tid; i < NTOK*128; i += 256) {
        int t = i >> 7, ch = i & 127;
        int v = hist[(b*128 + ch)*NTOK + t];
        A[t][ch] = v; orig[t][ch] = v;
    }
    __syncthreads();
    for (int d = 1; d < 128; d <<= 1) {
        for (int i = tid; i < NTOK*128; i += 256) {
            int t = i >> 7, ch = i & 127;
            Bf[t][ch] = A[t][ch] + ((ch >= d) ? A[t][ch-d] : 0);
        }
        __syncthreads();
        for (int i = tid; i < NTOK*128; i += 256) {
            int t = i >> 7, ch = i & 127;
            A[t][ch] = Bf[t][ch];
        }
        __syncthreads();
    }
    if (tid == 0) {
        int run = 0;
        for (int t = 0; t < NTOK; ++t) { cb[t] = run; run += A[t][127]; }
    }
    __syncthreads();
    for (int i = tid; i < NTOK*128; i += 256) {
        int t = i >> 7, ch = i & 127;
        base[(b*128 + ch)*NTOK + t] = cb[t] + A[t][ch] - orig[t][ch];
    }
}

__global__ void __launch_bounds__(256) k_scatteridx(
    const int* __restrict__ belong, const int* __restrict__ base,
    int* __restrict__ idx, int* __restrict__ inv) {
    int b = blockIdx.y, ch = blockIdx.x, tid = threadIdx.x;
    __shared__ int wc[4][NTOK];
    __shared__ int woff[4][NTOK];
    int n = ch*256 + tid;
    int myt = belong[b*NN + n];
    int w = tid >> 6, lane = tid & 63;
    unsigned long long mymask = 0;
#pragma unroll
    for (int t = 0; t < NTOK; ++t) {
        unsigned long long m = __ballot(myt == t);
        if (myt == t) mymask = m;
        if (lane == 0) wc[w][t] = __popcll(m);
    }
    __syncthreads();
    if (tid < 32) {
        int w2 = tid >> 3, t = tid & 7;
        int s = 0;
        for (int ww = 0; ww < w2; ++ww) s += wc[ww][t];
        woff[w2][t] = s;
    }
    __syncthreads();
    int rank = __popcll(mymask & ((1ull << lane) - 1ull));
    int p = base[(b*128+ch)*NTOK + myt] + woff[w][myt] + rank;
    idx[b*NN + p] = n;
    inv[b*NN + n] = p;
}

// ---------------------------------------------------------------------------
// q/k/v = gather(xn, idx) @ {Wq,Wk,Wv}; 128-row tile, thread = 8n x 6c
// outputs in sorted order, (b, p, 96)
// ---------------------------------------------------------------------------
__global__ void __launch_bounds__(256) k_qkv(
    const float* __restrict__ xn, const int* __restrict__ idx,
    const float* __restrict__ Wq, const float* __restrict__ Wk, const float* __restrict__ Wv,
    float* __restrict__ qs, float* __restrict__ ks, float* __restrict__ vs) {
    __shared__ __align__(16) float xnT[NC][132];
    __shared__ __align__(16) float wch[32][NC];
    __shared__ int idxl[128];
    int b = blockIdx.y; int p0 = blockIdx.x * 128; int tid = threadIdx.x;
    if (tid < 128) idxl[tid] = idx[b*NN + p0 + tid];
    __syncthreads();
    for (int i = tid; i < 128*NC; i += 256) {
        int p = i / NC, c = i % NC;
        xnT[c][p] = xn[((size_t)b*NN + idxl[p])*NC + c];
    }
    int cx = tid & 15, ny = tid >> 4;   // c = cx*6, n = ny*8
    const float* Ws[3] = {Wq, Wk, Wv};
    float* Os[3] = {qs, ks, vs};
    for (int m = 0; m < 3; ++m) {
        float acc[8][6];
#pragma unroll
        for (int i = 0; i < 8; ++i)
#pragma unroll
            for (int j = 0; j < 6; ++j) acc[i][j] = 0.f;
        const float* W = Ws[m];
        for (int kc = 0; kc < NC; kc += 32) {
            __syncthreads();
            for (int i = tid; i < 32*NC; i += 256) {
                int kk = i / NC, c = i % NC;
                wch[kk][c] = W[(kc+kk)*NC + c];
            }
            __syncthreads();
            for (int kk = 0; kk < 32; ++kk) {
                f4 a0 = *(const f4*)&xnT[kc+kk][ny*8];
                f4 a1 = *(const f4*)&xnT[kc+kk][ny*8+4];
                float a[8] = {a0.x,a0.y,a0.z,a0.w,a1.x,a1.y,a1.z,a1.w};
                float2 w0 = *(const float2*)&wch[kk][cx*6];
                float2 w1 = *(const float2*)&wch[kk][cx*6+2];
                float2 w2 = *(const float2*)&wch[kk][cx*6+4];
                float bb[6] = {w0.x,w0.y,w1.x,w1.y,w2.x,w2.y};
#pragma unroll
                for (int i = 0; i < 8; ++i)
#pragma unroll
                    for (int j = 0; j < 6; ++j) acc[i][j] += a[i]*bb[j];
            }
        }
        float* O = Os[m];
#pragma unroll
        for (int i = 0; i < 8; ++i) {
            size_t off = ((size_t)b*NN + p0 + ny*8 + i)*NC + cx*6;
            float2 s0 = {acc[i][0], acc[i][1]};
            float2 s1 = {acc[i][2], acc[i][3]};
            float2 s2 = {acc[i][4], acc[i][5]};
            *(float2*)&O[off]   = s0;
            *(float2*)&O[off+2] = s1;
            *(float2*)&O[off+4] = s2;
        }
    }
}

// ---------------------------------------------------------------------------
// Windowed attention (256 keys/group, online softmax, 2 threads per q-row)
// + global attention over 8 cluster tokens; outputs summed. (b,g,h) blocks.
// ---------------------------------------------------------------------------
__global__ void __launch_bounds__(256) k_attn(
    const float* __restrict__ qs, const float* __restrict__ ks, const float* __restrict__ vs,
    const float* __restrict__ kg, const float* __restrict__ vg,
    float* __restrict__ attn) {
    __shared__ f4 k4[256][4];
    __shared__ f4 v4[256][4];
    __shared__ f4 kg4[NTOK][4];
    __shared__ f4 vg4[NTOK][4];
    __shared__ float mrg[128][35];   // m, l, acc[16], out2[16] (34 used)
    int g = blockIdx.x, h = blockIdx.y, b = blockIdx.z;
    int tid = threadIdx.x;
    int row = tid & 127, half = tid >> 7;
    {
        int r = tid;
        int src = g*GSZ + r;
        if (g == NGRP-1 && r >= GSZ) src = NN - 1 - (r - GSZ);
        const f4* kp = (const f4*)&ks[((size_t)b*NN + src)*NC + h*16];
        const f4* vp = (const f4*)&vs[((size_t)b*NN + src)*NC + h*16];
#pragma unroll
        for (int i = 0; i < 4; ++i) { k4[r][i] = kp[i]; v4[r][i] = vp[i]; }
    }
    if (tid < NTOK) {
        const f4* kp = (const f4*)&kg[(h*NTOK + tid)*16];
        const f4* vp = (const f4*)&vg[(h*NTOK + tid)*16];
#pragma unroll
        for (int i = 0; i < 4; ++i) { kg4[tid][i] = kp[i]; vg4[tid][i] = vp[i]; }
    }
    float qv[16];
    {
        const f4* qp = (const f4*)&qs[((size_t)b*NN + g*GSZ + row)*NC + h*16];
#pragma unroll
        for (int i = 0; i < 4; ++i) {
            f4 t = qp[i];
            qv[i*4+0]=t.x; qv[i*4+1]=t.y; qv[i*4+2]=t.z; qv[i*4+3]=t.w;
        }
    }
    __syncthreads();
    const float scale = 0.25f;
    float m = -1e30f, l = 0.f;
    float acc[16];
#pragma unroll
    for (int e = 0; e < 16; ++e) acc[e] = 0.f;
    int k0 = half * GSZ;
    for (int kk = 0; kk < GSZ; ++kk) {
        int ki = k0 + kk;
        float kv[16], vv[16];
#pragma unroll
        for (int i = 0; i < 4; ++i) {
            f4 t = k4[ki][i];
            kv[i*4+0]=t.x; kv[i*4+1]=t.y; kv[i*4+2]=t.z; kv[i*4+3]=t.w;
            f4 u = v4[ki][i];
            vv[i*4+0]=u.x; vv[i*4+1]=u.y; vv[i*4+2]=u.z; vv[i*4+3]=u.w;
        }
        float s = 0.f;
#pragma unroll
        for (int e = 0; e < 16; ++e) s += qv[e]*kv[e];
        s *= scale;
        if (s > m) {
            float corr = __expf(m - s);
            l = l*corr + 1.f;
#pragma unroll
            for (int e = 0; e < 16; ++e) acc[e] = acc[e]*corr + vv[e];
            m = s;
        } else {
            float p = __expf(s - m);
            l += p;
#pragma unroll
            for (int e = 0; e < 16; ++e) acc[e] += p*vv[e];
        }
    }
    if (half == 0) {
        // global attention over 8 cluster tokens (separate softmax)
        float m2 = -1e30f, l2 = 0.f;
        float a2[16];
#pragma unroll
        for (int e = 0; e < 16; ++e) a2[e] = 0.f;
#pragma unroll
        for (int t = 0; t < NTOK; ++t) {
            float kv[16], vv[16];
#pragma unroll
            for (int i = 0; i < 4; ++i) {
                f4 tt = kg4[t][i];
                kv[i*4+0]=tt.x; kv[i*4+1]=tt.y; kv[i*4+2]=tt.z; kv[i*4+3]=tt.w;
                f4 uu = vg4[t][i];
                vv[i*4+0]=uu.x; vv[i*4+1]=uu.y; vv[i*4+2]=uu.z; vv[i*4+3]=uu.w;
            }
            float s = 0.f;
#pragma unroll
            for (int e = 0; e < 16; ++e) s += qv[e]*kv[e];
            s *= scale;
            if (s > m2) {
                float corr = __expf(m2 - s);
                l2 = l2*corr + 1.f;
#pragma unroll
                for (int e = 0; e < 16; ++e) a2[e] = a2[e]*corr + vv[e];
                m2 = s;
            } else {
                float p = __expf(s - m2);
                l2 += p;
#pragma unroll
                for (int e = 0; e < 16; ++e) a2[e] += p*vv[e];
            }
        }
        float inv2 = 1.f / l2;
        mrg[row][0] = m; mrg[row][1] = l;
#pragma unroll
        for (int e = 0; e < 16; ++e) mrg[row][2+e] = acc[e];
#pragma unroll
        for (int e = 0; e < 16; ++e) mrg[row][18+e] = a2[e]*inv2;
    }
    __syncthreads();
    if (half == 1) {
        float m0 = mrg[row][0], l0 = mrg[row][1];
        float mw = fmaxf(m0, m);
        float e0 = __expf(m0 - mw), e1 = __expf(m - mw);
        float lw = l0*e0 + l*e1;
        float invw = 1.f / lw;
        float o[16];
#pragma unroll
        for (int e = 0; e < 16; ++e)
            o[e] = (mrg[row][2+e]*e0 + acc[e]*e1)*invw + mrg[row][18+e];
        f4* op = (f4*)&attn[((size_t)b*NN + g*GSZ + row)*NC + h*16];
#pragma unroll
        for (int i = 0; i < 4; ++i) {
            f4 t = {o[i*4+0], o[i*4+1], o[i*4+2], o[i*4+3]};
            op[i] = t;
        }
    }
}

// ---------------------------------------------------------------------------
// Scatter back (inv), @ (Wproj@Wconv), + residual x; writes xrt in (b,c,n)
// ---------------------------------------------------------------------------
__global__ void __launch_bounds__(256) k_scatproj(
    const float* __restrict__ attn, const int* __restrict__ inv,
    const float* __restrict__ wpc, const float* __restrict__ x,
    float* __restrict__ xrt) {
    __shared__ __align__(16) float attT[NC][68];
    __shared__ __align__(16) float wch[32][NC];
    __shared__ int invl[64];
    int b = blockIdx.y; int n0 = blockIdx.x * 64; int tid = threadIdx.x;
    if (tid < 64) invl[tid] = inv[b*NN + n0 + tid];
    __syncthreads();
    for (int i = tid; i < 64*NC; i += 256) {
        int n = i / NC, c = i % NC;
        attT[c][n] = attn[((size_t)b*NN + invl[n])*NC + c];
    }
    int nx = tid & 15, cy = tid >> 4;  // n = nx*4, c = cy*6
    float acc[4][6];
#pragma unroll
    for (int i = 0; i < 4; ++i)
#pragma unroll
        for (int j = 0; j < 6; ++j) acc[i][j] = 0.f;
    for (int kc = 0; kc < NC; kc += 32) {
        __syncthreads();
        for (int i = tid; i < 32*NC; i += 256) {
            int kk = i / NC, c = i % NC;
            wch[kk][c] = wpc[(kc+kk)*NC + c];
        }
        __syncthreads();
        for (int kk = 0; kk < 32; ++kk) {
            f4 a0 = *(const f4*)&attT[kc+kk][nx*4];
            float a[4] = {a0.x,a0.y,a0.z,a0.w};
            float2 w0 = *(const float2*)&wch[kk][cy*6];
            float2 w1 = *(const float2*)&wch[kk][cy*6+2];
            float2 w2 = *(const float2*)&wch[kk][cy*6+4];
            float bb[6] = {w0.x,w0.y,w1.x,w1.y,w2.x,w2.y};
#pragma unroll
            for (int i = 0; i < 4; ++i)
#pragma unroll
                for (int j = 0; j < 6; ++j) acc[i][j] += a[i]*bb[j];
        }
    }
#pragma unroll
    for (int j = 0; j < 6; ++j) {
        int c = cy*6 + j;
        size_t off = ((size_t)b*NC + c)*NN + n0 + nx*4;
        f4 xv = *(const f4*)&x[off];
        f4 o = {acc[0][j]+xv.x, acc[1][j]+xv.y, acc[2][j]+xv.z, acc[3][j]+xv.w};
        *(f4*)&xrt[off] = o;
    }
}

// ---------------------------------------------------------------------------
// LN2 + @W1 + b1 + GELU; reads xrt (b,c,n), writes z1t (b, m, n)
// ---------------------------------------------------------------------------
__global__ void __launch_bounds__(256) k_mlp1(
    const float* __restrict__ xrt, const float* __restrict__ g2, const float* __restrict__ b2v,
    const float* __restrict__ W1, const float* __restrict__ b1m,
    float* __restrict__ z1t) {
    __shared__ __align__(16) float xt[NC][68];
    __shared__ __align__(16) float wch[32][NMLP];
    __shared__ float meanl[64], rstdl[64];
    __shared__ float gl[NC], bl[NC];
    int b = blockIdx.y; int n0 = blockIdx.x*64; int tid = threadIdx.x;
    if (tid < NC) { gl[tid] = g2[tid]; bl[tid] = b2v[tid]; }
    for (int i = tid; i < NC*64; i += 256) {
        int c = i >> 6, n = i & 63;
        xt[c][n] = xrt[((size_t)b*NC + c)*NN + n0 + n];
    }
    __syncthreads();
    int lane = tid & 63, w = tid >> 6;
    for (int tk = 0; tk < 16; ++tk) {
        int tok = w*16 + tk;
        float a  = xt[lane][tok];
        float bb = (lane < 32) ? xt[64+lane][tok] : 0.f;
        float s = a + bb, sq = a*a + bb*bb;
#pragma unroll
        for (int off = 32; off > 0; off >>= 1) {
            s  += __shfl_xor(s, off);
            sq += __shfl_xor(sq, off);
        }
        if (lane == 0) {
            float mean = s * (1.0f/NC);
            float var  = sq * (1.0f/NC) - mean*mean;
            meanl[tok] = mean; rstdl[tok] = rsqrtf(var + 1e-5f);
        }
    }
    __syncthreads();
    for (int i = tid; i < NC*64; i += 256) {
        int c = i >> 6, n = i & 63;
        xt[c][n] = (xt[c][n]-meanl[n])*rstdl[n]*gl[c]+bl[c];
    }
    int nx = tid & 15, my = tid >> 4;  // n = nx*4, m = my*12
    float acc[4][12];
#pragma unroll
    for (int i = 0; i < 4; ++i)
#pragma unroll
        for (int j = 0; j < 12; ++j) acc[i][j] = 0.f;
    for (int kc = 0; kc < NC; kc += 32) {
        __syncthreads();
        for (int i = tid; i < 32*NMLP; i += 256) {
            int kk = i / NMLP, c = i % NMLP;
            wch[kk][c] = W1[(kc+kk)*NMLP + c];
        }
        __syncthreads();
        for (int kk = 0; kk < 32; ++kk) {
            f4 a0 = *(const f4*)&xt[kc+kk][nx*4];
            float a[4] = {a0.x,a0.y,a0.z,a0.w};
            f4 w0 = *(const f4*)&wch[kk][my*12];
            f4 w1 = *(const f4*)&wch[kk][my*12+4];
            f4 w2 = *(const f4*)&wch[kk][my*12+8];
            float bb[12] = {w0.x,w0.y,w0.z,w0.w,w1.x,w1.y,w1.z,w1.w,w2.x,w2.y,w2.z,w2.w};
#pragma unroll
            for (int i = 0; i < 4; ++i)
#pragma unroll
                for (int j = 0; j < 12; ++j) acc[i][j] += a[i]*bb[j];
        }
    }
#pragma unroll
    for (int j = 0; j < 12; ++j) {
        int mm = my*12 + j;
        float bias = b1m[mm];
        size_t off = ((size_t)b*NMLP + mm)*NN + n0 + nx*4;
        f4 o = { gelu_f(acc[0][j]+bias), gelu_f(acc[1][j]+bias),
                 gelu_f(acc[2][j]+bias), gelu_f(acc[3][j]+bias) };
        *(f4*)&z1t[off] = o;
    }
}

// ---------------------------------------------------------------------------
// Depthwise 5x5x5 conv (pad 2) + GELU + add z1; z2t (b,m,n), register-blocked
// ---------------------------------------------------------------------------
__global__ void __launch_bounds__(256) k_dwconv(
    const float* __restrict__ z1t, const float* __restrict__ Wdw, const float* __restrict__ bdw,
    float* __restrict__ z2t) {
    __shared__ __align__(16) float tin[ND][20][72];
    __shared__ float wl[128];
    int ht = blockIdx.x, mch = blockIdx.y, b = blockIdx.z;
    int h0 = ht*16; int tid = threadIdx.x;
    if (tid < 125) wl[tid] = Wdw[mch*125 + tid];
    const float* src = &z1t[((size_t)b*NMLP + mch)*NN];
    for (int i = tid; i < ND*20*68; i += 256) {
        int dd = i / (20*68); int r = i % (20*68); int hh = r / 68; int ww = r % 68;
        int gh = h0 + hh - 2, gw = ww - 2;
        float v = 0.f;
        if ((unsigned)gh < 64u && (unsigned)gw < 64u) v = src[dd*4096 + gh*64 + gw];
        tin[dd][hh][ww] = v;
    }
    __syncthreads();
    int rowid = tid >> 1; int od = rowid >> 4; int ohl = rowid & 15; int wb = (tid & 1)*32;
    float acc[32];
#pragma unroll
    for (int o = 0; o < 32; ++o) acc[o] = 0.f;
    for (int kd = 0; kd < 5; ++kd) {
        int id = od + kd - 2;
        if ((unsigned)id >= (unsigned)ND) continue;
#pragma unroll
        for (int kh = 0; kh < 5; ++kh) {
            const float* rp = &tin[id][ohl+kh][wb];
            float seg[36];
#pragma unroll
            for (int i = 0; i < 9; ++i) *(f4*)&seg[i*4] = *(const f4*)&rp[i*4];
#pragma unroll
            for (int kw = 0; kw < 5; ++kw) {
                float wt = wl[kd*25 + kh*5 + kw];
#pragma unroll
                for (int o = 0; o < 32; ++o) acc[o] += seg[o+kw]*wt;
            }
        }
    }
    float bias = bdw[mch];
    float* dst = &z2t[((size_t)b*NMLP + mch)*NN + od*4096 + (size_t)(h0+ohl)*64 + wb];
    const float* ctr = &tin[od][ohl+2][wb+2];
#pragma unroll
    for (int o4 = 0; o4 < 32; o4 += 4) {
        f4 ov = { ctr[o4+0] + gelu_f(acc[o4+0]+bias),
                  ctr[o4+1] + gelu_f(acc[o4+1]+bias),
                  ctr[o4+2] + gelu_f(acc[o4+2]+bias),
                  ctr[o4+3] + gelu_f(acc[o4+3]+bias) };
        *(f4*)&dst[o4] = ov;
    }
}

// ---------------------------------------------------------------------------
// Final: out(b,c,n) = z2 @ W2 + b2 + xrt ; 128-token tile, thread = 8n x 6c
// ---------------------------------------------------------------------------
__global__ void __launch_bounds__(256) k_final(
    const float* __restrict__ z2t, const float* __restrict__ W2, const float* __restrict__ b2m,
    const float* __restrict__ xrt, float* __restrict__ out) {
    __shared__ __align__(16) float zch[32][132];
    __shared__ __align__(16) float wch[32][NC];
    int b = blockIdx.y; int n0 = blockIdx.x*128; int tid = threadIdx.x;
    int nx = tid & 15, cy = tid >> 4;   // n = nx*8, c = cy*6
    float acc[8][6];
#pragma unroll
    for (int i = 0; i < 8; ++i)
#pragma unroll
        for (int j = 0; j < 6; ++j) acc[i][j] = 0.f;
    for (int kc = 0; kc < NMLP; kc += 32) {
        __syncthreads();
        for (int i = tid; i < 32*128; i += 256) {
            int kk = i >> 7, n = i & 127;
            zch[kk][n] = z2t[((size_t)b*NMLP + kc + kk)*NN + n0 + n];
        }
        for (int i = tid; i < 32*NC; i += 256) {
            int kk = i / NC, c = i % NC;
            wch[kk][c] = W2[(kc+kk)*NC + c];
        }
        __syncthreads();
        for (int kk = 0; kk < 32; ++kk) {
            f4 a0 = *(const f4*)&zch[kk][nx*8];
            f4 a1 = *(const f4*)&zch[kk][nx*8+4];
            float a[8] = {a0.x,a0.y,a0.z,a0.w,a1.x,a1.y,a1.z,a1.w};
            float2 w0 = *(const float2*)&wch[kk][cy*6];
            float2 w1 = *(const float2*)&wch[kk][cy*6+2];
            float2 w2 = *(const float2*)&wch[kk][cy*6+4];
            float bb[6] = {w0.x,w0.y,w1.x,w1.y,w2.x,w2.y};
#pragma unroll
            for (int i = 0; i < 8; ++i)
#pragma unroll
                for (int j = 0; j < 6; ++j) acc[i][j] += a[i]*bb[j];
        }
    }
#pragma unroll
    for (int j = 0; j < 6; ++j) {
        int c = cy*6 + j;
        float bias = b2m[c];
        size_t off = ((size_t)b*NC + c)*NN + n0 + nx*8;
        f4 x0 = *(const f4*)&xrt[off];
        f4 x1 = *(const f4*)&xrt[off+4];
        f4 o0 = {acc[0][j]+bias+x0.x, acc[1][j]+bias+x0.y, acc[2][j]+bias+x0.z, acc[3][j]+bias+x0.w};
        f4 o1 = {acc[4][j]+bias+x1.x, acc[5][j]+bias+x1.y, acc[6][j]+bias+x1.z, acc[7][j]+bias+x1.w};
        *(f4*)&out[off]   = o0;
        *(f4*)&out[off+4] = o1;
    }
}

// ---------------------------------------------------------------------------
extern "C" void kernel_launch(void* const* d_in, const int* in_sizes, int n_in,
                              void* d_out, int out_size, void* d_ws, size_t ws_size,
                              hipStream_t stream) {
    (void)in_sizes; (void)n_in; (void)out_size; (void)ws_size;
    const float* x     = (const float*)d_in[0];
    const float* means = (const float*)d_in[1];
    const float* ln1_g = (const float*)d_in[2];
    const float* ln1_b = (const float*)d_in[3];
    const float* Wkg   = (const float*)d_in[4];
    const float* Wvg   = (const float*)d_in[5];
    const float* Wq    = (const float*)d_in[6];
    const float* Wk    = (const float*)d_in[7];
    const float* Wv    = (const float*)d_in[8];
    const float* Wproj = (const float*)d_in[9];
    const float* Wconv = (const float*)d_in[10];
    const float* ln2_g = (const float*)d_in[11];
    const float* ln2_b = (const float*)d_in[12];
    const float* W1    = (const float*)d_in[13];
    const float* b1    = (const float*)d_in[14];
    const float* Wdw   = (const float*)d_in[15];
    const float* bdw   = (const float*)d_in[16];
    const float* W2    = (const float*)d_in[17];
    const float* b2    = (const float*)d_in[18];
    float* out = (float*)d_out;

    float* ws = (float*)d_ws;
    const size_t SZ = (size_t)NB*NN*NC;
    float* xn   = ws;
    float* qs   = ws + SZ;
    float* ks   = ws + 2*SZ;
    float* vs   = ws + 3*SZ;
    float* attn = ws + 4*SZ;
    float* xrt  = ws;          // reuse xn (dead after k_qkv)
    float* z1t  = ws + SZ;     // reuse qs,ks (dead after k_attn)
    float* z2t  = ws + 3*SZ;   // reuse vs,attn (dead after k_scatproj.. k_dwconv input is z1t)
    float* faux = ws + 5*SZ;
    float* mnn  = faux;            // 768
    float* gdot = faux + 768;      // 8
    float* bdot = faux + 776;      // 8
    float* kg   = faux + 784;      // 768
    float* vg   = faux + 1552;     // 768
    float* wpc  = faux + 2320;     // 9216 -> ends at 11536
    int* iaux   = (int*)(faux + 11536);
    int* belong = iaux;                  // NB*NN
    int* idx    = iaux + NB*NN;          // NB*NN
    int* inv    = iaux + 2*NB*NN;        // NB*NN
    int* hist   = iaux + 3*NB*NN;        // NB*128*8
    int* baseb  = hist + NB*128*NTOK;    // NB*128*8

    k_precompute<<<dim3(1), dim3(256), 0, stream>>>(
        means, ln1_g, ln1_b, Wkg, Wvg, Wproj, Wconv, mnn, gdot, bdot, kg, vg, wpc);
    k_ln1<<<dim3(NN/64, NB), dim3(256), 0, stream>>>(
        x, ln1_g, ln1_b, mnn, gdot, bdot, xn, belong);
    k_hist<<<dim3(NN/256, NB), dim3(256), 0, stream>>>(belong, hist);
    k_scan<<<dim3(NB), dim3(256), 0, stream>>>(hist, baseb);
    k_scatteridx<<<dim3(NN/256, NB), dim3(256), 0, stream>>>(belong, baseb, idx, inv);
    k_qkv<<<dim3(NN/128, NB), dim3(256), 0, stream>>>(xn, idx, Wq, Wk, Wv, qs, ks, vs);
    k_attn<<<dim3(NGRP, NHEADS, NB), dim3(256), 0, stream>>>(qs, ks, vs, kg, vg, attn);
    k_scatproj<<<dim3(NN/64, NB), dim3(256), 0, stream>>>(attn, inv, wpc, x, xrt);
    k_mlp1<<<dim3(NN/64, NB), dim3(256), 0, stream>>>(xrt, ln2_g, ln2_b, W1, b1, z1t);
    k_dwconv<<<dim3(4, NMLP, NB), dim3(256), 0, stream>>>(z1t, Wdw, bdw, z2t);
    k_final<<<dim3(NN/128, NB), dim3(256), 0, stream>>>(z2t, W2, b2, xrt, out);
}

// Round 5
// 698.413 us; speedup vs baseline: 1.1517x; 1.1517x over previous
//
#include <hip/hip_runtime.h>
#include <math.h>

#define NB 2
#define NC 96
#define ND 8
#define NHH 64
#define NWW 64
#define NN 32768          // ND*NHH*NWW
#define NTOK 8
#define NHEADS 6
#define GSZ 128
#define NGRP 256          // NN/GSZ
#define NMLP 192

typedef float4 f4;

__device__ __forceinline__ float gelu_f(float x) {
    return 0.5f * x * (1.0f + erff(x * 0.70710678118654752440f));
}

// ---------------------------------------------------------------------------
// Precompute (grid=5): blk0: normalized means, gdot/bdot, kg/vg.
// blk1..4: wpc = Wproj @ Wconv, 24 rows each, fully LDS-staged.
// ---------------------------------------------------------------------------
__global__ void __launch_bounds__(256) k_precompute(
    const float* __restrict__ means, const float* __restrict__ g1, const float* __restrict__ b1v,
    const float* __restrict__ Wkg, const float* __restrict__ Wvg,
    const float* __restrict__ Wproj, const float* __restrict__ Wconv,
    float* __restrict__ mnn, float* __restrict__ gdot, float* __restrict__ bdot,
    float* __restrict__ kg, float* __restrict__ vg, float* __restrict__ wpc) {
    int blk = blockIdx.x; int tid = threadIdx.x;
    if (blk == 0) {
        __shared__ float mlds[NTOK*NC];
        __shared__ float glds[NC], blds[NC];
        for (int i = tid; i < NTOK*NC; i += 256) mlds[i] = means[i];
        if (tid < NC) { glds[tid] = g1[tid]; blds[tid] = b1v[tid]; }
        __syncthreads();
        if (tid < NTOK) {
            float ss = 0.f;
            for (int c = 0; c < NC; ++c) { float v = mlds[tid*NC+c]; ss += v*v; }
            float inv = 1.0f / fmaxf(sqrtf(ss), 1e-12f);
            float gd = 0.f, bd = 0.f;
            for (int c = 0; c < NC; ++c) {
                float v = mlds[tid*NC+c] * inv;
                mnn[tid*NC+c] = v;
                gd += glds[c]*v; bd += blds[c]*v;
            }
            gdot[tid] = gd; bdot[tid] = bd;
        }
        // kg/vg: layout [h][t][e], e<16
        for (int i = tid; i < NHEADS*NTOK*16; i += 256) {
            int h = i / (NTOK*16); int r = i % (NTOK*16); int t = r / 16; int e = r % 16;
            float sk = 0.f, sv = 0.f;
            for (int c = 0; c < NC; ++c) {
                float mv = mlds[t*NC+c];
                sk += mv * Wkg[c*NC + h*16+e];
                sv += mv * Wvg[c*NC + h*16+e];
            }
            kg[i] = sk; vg[i] = sv;
        }
    } else {
        int r0 = (blk-1)*24;
        __shared__ float wcv[NC][NC];
        __shared__ float wpl[24][NC];
        for (int i = tid; i < NC*NC; i += 256) wcv[i/NC][i%NC] = Wconv[i];
        for (int i = tid; i < 24*NC; i += 256) wpl[i/NC][i%NC] = Wproj[(r0 + i/NC)*NC + i%NC];
        __syncthreads();
        for (int o = tid; o < 24*NC; o += 256) {
            int r = o / NC, c = o % NC;
            float s = 0.f;
            for (int k = 0; k < NC; ++k) s += wpl[r][k]*wcv[k][c];
            wpc[(r0+r)*NC + c] = s;
        }
    }
}

// ---------------------------------------------------------------------------
// LN1 (reads x in (b,c,n), writes xn in (b,n,c)) fused with cluster argmax.
// ---------------------------------------------------------------------------
__global__ void __launch_bounds__(256) k_ln1(
    const float* __restrict__ x, const float* __restrict__ g1, const float* __restrict__ b1v,
    const float* __restrict__ mnn, const float* __restrict__ gdot, const float* __restrict__ bdot,
    float* __restrict__ xn, int* __restrict__ belong) {
    __shared__ __align__(16) float xt[NC][68];
    __shared__ float meanl[64], rstdl[64];
    __shared__ float gl[NC], bl[NC], gdl[NTOK], bdl[NTOK];
    int b = blockIdx.y; int n0 = blockIdx.x * 64;
    int tid = threadIdx.x;
    if (tid < NC) { gl[tid] = g1[tid]; bl[tid] = b1v[tid]; }
    if (tid >= NC && tid < NC+NTOK) { gdl[tid-NC] = gdot[tid-NC]; bdl[tid-NC] = bdot[tid-NC]; }
    for (int i = tid; i < NC*64; i += 256) {
        int c = i >> 6, n = i & 63;
        xt[c][n] = x[((size_t)b*NC + c)*NN + n0 + n];
    }
    __syncthreads();
    int lane = tid & 63, w = tid >> 6;
    float ga = gl[lane];
    float gb = (lane < 32) ? gl[64+lane] : 0.f;
    float ma[NTOK], mb[NTOK];
#pragma unroll
    for (int t = 0; t < NTOK; ++t) {
        ma[t] = mnn[t*NC + lane];
        mb[t] = (lane < 32) ? mnn[t*NC + 64 + lane] : 0.f;
    }
    for (int tk = 0; tk < 16; ++tk) {
        int tok = w*16 + tk;
        float a  = xt[lane][tok];
        float bb = (lane < 32) ? xt[64+lane][tok] : 0.f;
        float red[10];
        red[0] = a + bb;
        red[1] = a*a + bb*bb;
        float ag = a*ga, bg = bb*gb;
#pragma unroll
        for (int t = 0; t < NTOK; ++t) red[2+t] = ag*ma[t] + bg*mb[t];
#pragma unroll
        for (int off = 32; off > 0; off >>= 1) {
#pragma unroll
            for (int r = 0; r < 10; ++r) red[r] += __shfl_xor(red[r], off);
        }
        if (lane == 0) {
            float mean = red[0] * (1.0f/NC);
            float var  = red[1] * (1.0f/NC) - mean*mean;
            float rstd = rsqrtf(var + 1e-5f);
            meanl[tok] = mean; rstdl[tok] = rstd;
            int best = 0; float bestv = -1e30f;
#pragma unroll
            for (int t = 0; t < NTOK; ++t) {
                float sc = rstd*(red[2+t] - mean*gdl[t]) + bdl[t];
                if (sc > bestv) { bestv = sc; best = t; }
            }
            belong[b*NN + n0 + tok] = best;
        }
    }
    __syncthreads();
    for (int i = tid; i < 64*NC; i += 256) {
        int n = i / NC, c = i % NC;
        float v = (xt[c][n] - meanl[n]) * rstdl[n] * gl[c] + bl[c];
        xn[((size_t)b*NN + n0 + n)*NC + c] = v;
    }
}

// ---------------------------------------------------------------------------
// Stable counting sort of `belong` (values 0..7): hist -> scan -> scatter
// ---------------------------------------------------------------------------
__global__ void __launch_bounds__(256) k_hist(const int* __restrict__ belong, int* __restrict__ hist) {
    int b = blockIdx.y, ch = blockIdx.x, tid = threadIdx.x;
    __shared__ int wc[4][NTOK];
    int myt = belong[b*NN + ch*256 + tid];
    int w = tid >> 6, lane = tid & 63;
#pragma unroll
    for (int t = 0; t < NTOK; ++t) {
        unsigned long long m = __ballot(myt == t);
        if (lane == 0) wc[w][t] = __popcll(m);
    }
    __syncthreads();
    if (tid < NTOK) hist[(b*128 + ch)*NTOK + tid] = wc[0][tid]+wc[1][tid]+wc[2][tid]+wc[3][tid];
}

__global__ void __launch_bounds__(256) k_scan(const int* __restrict__ hist, int* __restrict__ base) {
    int b = blockIdx.x, tid = threadIdx.x;
    __shared__ int A[NTOK][128], Bf[NTOK][128], orig[NTOK][128];
    __shared__ int cb[NTOK];
    for (int i = tid; i < NTOK*128; i += 256) {
        int t = i >> 7, ch = i & 127;
        int v = hist[(b*128 + ch)*NTOK + t];
        A[t][ch] = v; orig[t][ch] = v;
    }
    __syncthreads();
    for (int d = 1; d < 128; d <<= 1) {
        for (int i = tid; i < NTOK*128; i += 256) {
            int t = i >> 7, ch = i & 127;
            Bf[t][ch] = A[t][ch] + ((ch >= d) ? A[t][ch-d] : 0);
        }
        __syncthreads();
        for (int i = tid; i < NTOK*128; i += 256) {
            int t = i >> 7, ch = i & 127;
            A[t][ch] = Bf[t][ch];
        }
        __syncthreads();
    }
    if (tid == 0) {
        int run = 0;
        for (int t = 0; t < NTOK; ++t) { cb[t] = run; run += A[t][127]; }
    }
    __syncthreads();
    for (int i = tid; i < NTOK*128; i += 256) {
        int t = i >> 7, ch = i & 127;
        base[(b*128 + ch)*NTOK + t] = cb[t] + A[t][ch] - orig[t][ch];
    }
}

__global__ void __launch_bounds__(256) k_scatteridx(
    const int* __restrict__ belong, const int* __restrict__ base,
    int* __restrict__ idx, int* __restrict__ inv) {
    int b = blockIdx.y, ch = blockIdx.x, tid = threadIdx.x;
    __shared__ int wc[4][NTOK];
    __shared__ int woff[4][NTOK];
    int n = ch*256 + tid;
    int myt = belong[b*NN + n];
    int w = tid >> 6, lane = tid & 63;
    unsigned long long mymask = 0;
#pragma unroll
    for (int t = 0; t < NTOK; ++t) {
        unsigned long long m = __ballot(myt == t);
        if (myt == t) mymask = m;
        if (lane == 0) wc[w][t] = __popcll(m);
    }
    __syncthreads();
    if (tid < 32) {
        int w2 = tid >> 3, t = tid & 7;
        int s = 0;
        for (int ww = 0; ww < w2; ++ww) s += wc[ww][t];
        woff[w2][t] = s;
    }
    __syncthreads();
    int rank = __popcll(mymask & ((1ull << lane) - 1ull));
    int p = base[(b*128+ch)*NTOK + myt] + woff[w][myt] + rank;
    idx[b*NN + p] = n;
    inv[b*NN + n] = p;
}

// ---------------------------------------------------------------------------
// q/k/v = gather(xn, idx) @ {Wq,Wk,Wv}; 128-row tile, thread = 8n x 6c
// ---------------------------------------------------------------------------
__global__ void __launch_bounds__(256) k_qkv(
    const float* __restrict__ xn, const int* __restrict__ idx,
    const float* __restrict__ Wq, const float* __restrict__ Wk, const float* __restrict__ Wv,
    float* __restrict__ qs, float* __restrict__ ks, float* __restrict__ vs) {
    __shared__ __align__(16) float xnT[NC][132];
    __shared__ __align__(16) float wch[32][NC];
    __shared__ int idxl[128];
    int b = blockIdx.y; int p0 = blockIdx.x * 128; int tid = threadIdx.x;
    if (tid < 128) idxl[tid] = idx[b*NN + p0 + tid];
    __syncthreads();
    for (int i = tid; i < 128*NC; i += 256) {
        int p = i / NC, c = i % NC;
        xnT[c][p] = xn[((size_t)b*NN + idxl[p])*NC + c];
    }
    int cx = tid & 15, ny = tid >> 4;   // c = cx*6, n = ny*8
    const float* Ws[3] = {Wq, Wk, Wv};
    float* Os[3] = {qs, ks, vs};
    for (int m = 0; m < 3; ++m) {
        float acc[8][6];
#pragma unroll
        for (int i = 0; i < 8; ++i)
#pragma unroll
            for (int j = 0; j < 6; ++j) acc[i][j] = 0.f;
        const float* W = Ws[m];
        for (int kc = 0; kc < NC; kc += 32) {
            __syncthreads();
            for (int i = tid; i < 32*NC; i += 256) {
                int kk = i / NC, c = i % NC;
                wch[kk][c] = W[(kc+kk)*NC + c];
            }
            __syncthreads();
            for (int kk = 0; kk < 32; ++kk) {
                f4 a0 = *(const f4*)&xnT[kc+kk][ny*8];
                f4 a1 = *(const f4*)&xnT[kc+kk][ny*8+4];
                float a[8] = {a0.x,a0.y,a0.z,a0.w,a1.x,a1.y,a1.z,a1.w};
                float2 w0 = *(const float2*)&wch[kk][cx*6];
                float2 w1 = *(const float2*)&wch[kk][cx*6+2];
                float2 w2 = *(const float2*)&wch[kk][cx*6+4];
                float bb[6] = {w0.x,w0.y,w1.x,w1.y,w2.x,w2.y};
#pragma unroll
                for (int i = 0; i < 8; ++i)
#pragma unroll
                    for (int j = 0; j < 6; ++j) acc[i][j] += a[i]*bb[j];
            }
        }
        float* O = Os[m];
#pragma unroll
        for (int i = 0; i < 8; ++i) {
            size_t off = ((size_t)b*NN + p0 + ny*8 + i)*NC + cx*6;
            float2 s0 = {acc[i][0], acc[i][1]};
            float2 s1 = {acc[i][2], acc[i][3]};
            float2 s2 = {acc[i][4], acc[i][5]};
            *(float2*)&O[off]   = s0;
            *(float2*)&O[off+2] = s1;
            *(float2*)&O[off+4] = s2;
        }
    }
}

// ---------------------------------------------------------------------------
// Windowed attention, restructured: 4 waves/block, thread = (row, half),
// halves of a row at lanes +/-32 of the same wave -> shfl merge, no LDS mrg.
// Chunked-branchless online softmax (8 keys/chunk). Scale folded into q.
// ---------------------------------------------------------------------------
__global__ void __launch_bounds__(256, 4) k_attn(
    const float* __restrict__ qs, const float* __restrict__ ks, const float* __restrict__ vs,
    const float* __restrict__ kg, const float* __restrict__ vg,
    float* __restrict__ attn) {
    __shared__ __align__(16) f4 kt[256][4];
    __shared__ __align__(16) f4 vt[256][4];
    __shared__ __align__(16) f4 kgs[NTOK][4];
    __shared__ __align__(16) f4 vgs[NTOK][4];
    int g = blockIdx.x, h = blockIdx.y, b = blockIdx.z;
    int tid = threadIdx.x;
    for (int i = tid; i < 1024; i += 256) {
        int r = i >> 2, c = i & 3;
        int src = g*GSZ + r;
        if (g == NGRP-1 && r >= GSZ) src = NN - 1 - (r - GSZ);
        size_t off = ((size_t)b*NN + src)*NC + h*16 + c*4;
        kt[r][c] = *(const f4*)&ks[off];
        vt[r][c] = *(const f4*)&vs[off];
    }
    if (tid < 32) {
        int t = tid >> 2, c = tid & 3;
        kgs[t][c] = *(const f4*)&kg[(h*NTOK + t)*16 + c*4];
        vgs[t][c] = *(const f4*)&vg[(h*NTOK + t)*16 + c*4];
    }
    int wv = tid >> 6, lane = tid & 63;
    int row = wv*32 + (lane & 31);
    int half = lane >> 5;
    float qv[16];
    {
        const f4* qp = (const f4*)&qs[((size_t)b*NN + g*GSZ + row)*NC + h*16];
#pragma unroll
        for (int i = 0; i < 4; ++i) {
            f4 t = qp[i];
            qv[i*4+0]=t.x*0.25f; qv[i*4+1]=t.y*0.25f; qv[i*4+2]=t.z*0.25f; qv[i*4+3]=t.w*0.25f;
        }
    }
    __syncthreads();
    float m = -1e30f, l = 0.f;
    float acc[16];
#pragma unroll
    for (int e = 0; e < 16; ++e) acc[e] = 0.f;
    int k0 = half * GSZ;
    for (int c8 = 0; c8 < 16; ++c8) {
        float s[8];
#pragma unroll
        for (int j = 0; j < 8; ++j) {
            const f4* kp = &kt[k0 + c8*8 + j][0];
            f4 ka = kp[0], kb = kp[1], kc = kp[2], kd = kp[3];
            s[j] = qv[0]*ka.x + qv[1]*ka.y + qv[2]*ka.z + qv[3]*ka.w
                 + qv[4]*kb.x + qv[5]*kb.y + qv[6]*kb.z + qv[7]*kb.w
                 + qv[8]*kc.x + qv[9]*kc.y + qv[10]*kc.z + qv[11]*kc.w
                 + qv[12]*kd.x + qv[13]*kd.y + qv[14]*kd.z + qv[15]*kd.w;
        }
        float cm = fmaxf(fmaxf(fmaxf(s[0],s[1]), fmaxf(s[2],s[3])),
                         fmaxf(fmaxf(s[4],s[5]), fmaxf(s[6],s[7])));
        float nm = fmaxf(m, cm);
        float corr = __expf(m - nm);
        m = nm;
        l *= corr;
#pragma unroll
        for (int e = 0; e < 16; ++e) acc[e] *= corr;
#pragma unroll
        for (int j = 0; j < 8; ++j) {
            float p = __expf(s[j] - m);
            l += p;
            const f4* vp = &vt[k0 + c8*8 + j][0];
            f4 va = vp[0], vb = vp[1], vc = vp[2], vd = vp[3];
            acc[0] += p*va.x; acc[1] += p*va.y; acc[2] += p*va.z; acc[3] += p*va.w;
            acc[4] += p*vb.x; acc[5] += p*vb.y; acc[6] += p*vb.z; acc[7] += p*vb.w;
            acc[8] += p*vc.x; acc[9] += p*vc.y; acc[10] += p*vc.z; acc[11] += p*vc.w;
            acc[12] += p*vd.x; acc[13] += p*vd.y; acc[14] += p*vd.z; acc[15] += p*vd.w;
        }
    }
    // global attention over 8 cluster tokens (redundant in both halves: no divergence)
    float m2 = -1e30f, l2 = 0.f;
    float a2[16];
#pragma unroll
    for (int e = 0; e < 16; ++e) a2[e] = 0.f;
#pragma unroll
    for (int t = 0; t < NTOK; ++t) {
        f4 ka = kgs[t][0], kb = kgs[t][1], kc = kgs[t][2], kd = kgs[t][3];
        float s = qv[0]*ka.x + qv[1]*ka.y + qv[2]*ka.z + qv[3]*ka.w
                + qv[4]*kb.x + qv[5]*kb.y + qv[6]*kb.z + qv[7]*kb.w
                + qv[8]*kc.x + qv[9]*kc.y + qv[10]*kc.z + qv[11]*kc.w
                + qv[12]*kd.x + qv[13]*kd.y + qv[14]*kd.z + qv[15]*kd.w;
        float nm2 = fmaxf(m2, s);
        float corr = __expf(m2 - nm2);
        m2 = nm2;
        l2 *= corr;
        float p = __expf(s - m2);
        l2 += p;
        f4 va = vgs[t][0], vb = vgs[t][1], vc = vgs[t][2], vd = vgs[t][3];
#pragma unroll
        for (int e = 0; e < 16; ++e) a2[e] *= corr;
        a2[0] += p*va.x; a2[1] += p*va.y; a2[2] += p*va.z; a2[3] += p*va.w;
        a2[4] += p*vb.x; a2[5] += p*vb.y; a2[6] += p*vb.z; a2[7] += p*vb.w;
        a2[8] += p*vc.x; a2[9] += p*vc.y; a2[10] += p*vc.z; a2[11] += p*vc.w;
        a2[12] += p*vd.x; a2[13] += p*vd.y; a2[14] += p*vd.z; a2[15] += p*vd.w;
    }
    float inv2 = 1.f / l2;
    // merge halves via shfl across lane ^ 32
    float om = __shfl_xor(m, 32);
    float ol = __shfl_xor(l, 32);
    float mw = fmaxf(m, om);
    float es = __expf(m - mw), eo = __expf(om - mw);
    float lw = l*es + ol*eo;
    float invw = 1.f / lw;
    float o[16];
#pragma unroll
    for (int e = 0; e < 16; ++e) {
        float oa = __shfl_xor(acc[e], 32);
        o[e] = (acc[e]*es + oa*eo)*invw + a2[e]*inv2;
    }
    if (half == 0) {
        f4* op = (f4*)&attn[((size_t)b*NN + g*GSZ + row)*NC + h*16];
#pragma unroll
        for (int i = 0; i < 4; ++i) {
            f4 t = {o[i*4+0], o[i*4+1], o[i*4+2], o[i*4+3]};
            op[i] = t;
        }
    }
}

// ---------------------------------------------------------------------------
// Scatter back (inv), @ (Wproj@Wconv), + residual x; writes xrt in (b,c,n)
// ---------------------------------------------------------------------------
__global__ void __launch_bounds__(256) k_scatproj(
    const float* __restrict__ attn, const int* __restrict__ inv,
    const float* __restrict__ wpc, const float* __restrict__ x,
    float* __restrict__ xrt) {
    __shared__ __align__(16) float attT[NC][68];
    __shared__ __align__(16) float wch[32][NC];
    __shared__ int invl[64];
    int b = blockIdx.y; int n0 = blockIdx.x * 64; int tid = threadIdx.x;
    if (tid < 64) invl[tid] = inv[b*NN + n0 + tid];
    __syncthreads();
    for (int i = tid; i < 64*NC; i += 256) {
        int n = i / NC, c = i % NC;
        attT[c][n] = attn[((size_t)b*NN + invl[n])*NC + c];
    }
    int nx = tid & 15, cy = tid >> 4;  // n = nx*4, c = cy*6
    float acc[4][6];
#pragma unroll
    for (int i = 0; i < 4; ++i)
#pragma unroll
        for (int j = 0; j < 6; ++j) acc[i][j] = 0.f;
    for (int kc = 0; kc < NC; kc += 32) {
        __syncthreads();
        for (int i = tid; i < 32*NC; i += 256) {
            int kk = i / NC, c = i % NC;
            wch[kk][c] = wpc[(kc+kk)*NC + c];
        }
        __syncthreads();
        for (int kk = 0; kk < 32; ++kk) {
            f4 a0 = *(const f4*)&attT[kc+kk][nx*4];
            float a[4] = {a0.x,a0.y,a0.z,a0.w};
            float2 w0 = *(const float2*)&wch[kk][cy*6];
            float2 w1 = *(const float2*)&wch[kk][cy*6+2];
            float2 w2 = *(const float2*)&wch[kk][cy*6+4];
            float bb[6] = {w0.x,w0.y,w1.x,w1.y,w2.x,w2.y};
#pragma unroll
            for (int i = 0; i < 4; ++i)
#pragma unroll
                for (int j = 0; j < 6; ++j) acc[i][j] += a[i]*bb[j];
        }
    }
#pragma unroll
    for (int j = 0; j < 6; ++j) {
        int c = cy*6 + j;
        size_t off = ((size_t)b*NC + c)*NN + n0 + nx*4;
        f4 xv = *(const f4*)&x[off];
        f4 o = {acc[0][j]+xv.x, acc[1][j]+xv.y, acc[2][j]+xv.z, acc[3][j]+xv.w};
        *(f4*)&xrt[off] = o;
    }
}

// ---------------------------------------------------------------------------
// LN2 + @W1 + b1 + GELU; reads xrt (b,c,n), writes z1t (b, m, n)
// ---------------------------------------------------------------------------
__global__ void __launch_bounds__(256) k_mlp1(
    const float* __restrict__ xrt, const float* __restrict__ g2, const float* __restrict__ b2v,
    const float* __restrict__ W1, const float* __restrict__ b1m,
    float* __restrict__ z1t) {
    __shared__ __align__(16) float xt[NC][68];
    __shared__ __align__(16) float wch[32][NMLP];
    __shared__ float meanl[64], rstdl[64];
    __shared__ float gl[NC], bl[NC];
    int b = blockIdx.y; int n0 = blockIdx.x*64; int tid = threadIdx.x;
    if (tid < NC) { gl[tid] = g2[tid]; bl[tid] = b2v[tid]; }
    for (int i = tid; i < NC*64; i += 256) {
        int c = i >> 6, n = i & 63;
        xt[c][n] = xrt[((size_t)b*NC + c)*NN + n0 + n];
    }
    __syncthreads();
    int lane = tid & 63, w = tid >> 6;
    for (int tk = 0; tk < 16; ++tk) {
        int tok = w*16 + tk;
        float a  = xt[lane][tok];
        float bb = (lane < 32) ? xt[64+lane][tok] : 0.f;
        float s = a + bb, sq = a*a + bb*bb;
#pragma unroll
        for (int off = 32; off > 0; off >>= 1) {
            s  += __shfl_xor(s, off);
            sq += __shfl_xor(sq, off);
        }
        if (lane == 0) {
            float mean = s * (1.0f/NC);
            float var  = sq * (1.0f/NC) - mean*mean;
            meanl[tok] = mean; rstdl[tok] = rsqrtf(var + 1e-5f);
        }
    }
    __syncthreads();
    for (int i = tid; i < NC*64; i += 256) {
        int c = i >> 6, n = i & 63;
        xt[c][n] = (xt[c][n]-meanl[n])*rstdl[n]*gl[c]+bl[c];
    }
    int nx = tid & 15, my = tid >> 4;  // n = nx*4, m = my*12
    float acc[4][12];
#pragma unroll
    for (int i = 0; i < 4; ++i)
#pragma unroll
        for (int j = 0; j < 12; ++j) acc[i][j] = 0.f;
    for (int kc = 0; kc < NC; kc += 32) {
        __syncthreads();
        for (int i = tid; i < 32*NMLP; i += 256) {
            int kk = i / NMLP, c = i % NMLP;
            wch[kk][c] = W1[(kc+kk)*NMLP + c];
        }
        __syncthreads();
        for (int kk = 0; kk < 32; ++kk) {
            f4 a0 = *(const f4*)&xt[kc+kk][nx*4];
            float a[4] = {a0.x,a0.y,a0.z,a0.w};
            f4 w0 = *(const f4*)&wch[kk][my*12];
            f4 w1 = *(const f4*)&wch[kk][my*12+4];
            f4 w2 = *(const f4*)&wch[kk][my*12+8];
            float bb[12] = {w0.x,w0.y,w0.z,w0.w,w1.x,w1.y,w1.z,w1.w,w2.x,w2.y,w2.z,w2.w};
#pragma unroll
            for (int i = 0; i < 4; ++i)
#pragma unroll
                for (int j = 0; j < 12; ++j) acc[i][j] += a[i]*bb[j];
        }
    }
#pragma unroll
    for (int j = 0; j < 12; ++j) {
        int mm = my*12 + j;
        float bias = b1m[mm];
        size_t off = ((size_t)b*NMLP + mm)*NN + n0 + nx*4;
        f4 o = { gelu_f(acc[0][j]+bias), gelu_f(acc[1][j]+bias),
                 gelu_f(acc[2][j]+bias), gelu_f(acc[3][j]+bias) };
        *(f4*)&z1t[off] = o;
    }
}

// ---------------------------------------------------------------------------
// Depthwise 5x5x5 conv (pad 2) + GELU + add z1; z2t (b,m,n), register-blocked
// ---------------------------------------------------------------------------
__global__ void __launch_bounds__(256) k_dwconv(
    const float* __restrict__ z1t, const float* __restrict__ Wdw, const float* __restrict__ bdw,
    float* __restrict__ z2t) {
    __shared__ __align__(16) float tin[ND][20][72];
    __shared__ float wl[128];
    int ht = blockIdx.x, mch = blockIdx.y, b = blockIdx.z;
    int h0 = ht*16; int tid = threadIdx.x;
    if (tid < 125) wl[tid] = Wdw[mch*125 + tid];
    const float* src = &z1t[((size_t)b*NMLP + mch)*NN];
    for (int i = tid; i < ND*20*68; i += 256) {
        int dd = i / (20*68); int r = i % (20*68); int hh = r / 68; int ww = r % 68;
        int gh = h0 + hh - 2, gw = ww - 2;
        float v = 0.f;
        if ((unsigned)gh < 64u && (unsigned)gw < 64u) v = src[dd*4096 + gh*64 + gw];
        tin[dd][hh][ww] = v;
    }
    __syncthreads();
    int rowid = tid >> 1; int od = rowid >> 4; int ohl = rowid & 15; int wb = (tid & 1)*32;
    float acc[32];
#pragma unroll
    for (int o = 0; o < 32; ++o) acc[o] = 0.f;
    for (int kd = 0; kd < 5; ++kd) {
        int id = od + kd - 2;
        if ((unsigned)id >= (unsigned)ND) continue;
#pragma unroll
        for (int kh = 0; kh < 5; ++kh) {
            const float* rp = &tin[id][ohl+kh][wb];
            float seg[36];
#pragma unroll
            for (int i = 0; i < 9; ++i) *(f4*)&seg[i*4] = *(const f4*)&rp[i*4];
#pragma unroll
            for (int kw = 0; kw < 5; ++kw) {
                float wt = wl[kd*25 + kh*5 + kw];
#pragma unroll
                for (int o = 0; o < 32; ++o) acc[o] += seg[o+kw]*wt;
            }
        }
    }
    float bias = bdw[mch];
    float* dst = &z2t[((size_t)b*NMLP + mch)*NN + od*4096 + (size_t)(h0+ohl)*64 + wb];
    const float* ctr = &tin[od][ohl+2][wb+2];
#pragma unroll
    for (int o4 = 0; o4 < 32; o4 += 4) {
        f4 ov = { ctr[o4+0] + gelu_f(acc[o4+0]+bias),
                  ctr[o4+1] + gelu_f(acc[o4+1]+bias),
                  ctr[o4+2] + gelu_f(acc[o4+2]+bias),
                  ctr[o4+3] + gelu_f(acc[o4+3]+bias) };
        *(f4*)&dst[o4] = ov;
    }
}

// ---------------------------------------------------------------------------
// Final: out(b,c,n) = z2 @ W2 + b2 + xrt ; 128-token tile, thread = 8n x 6c
// ---------------------------------------------------------------------------
__global__ void __launch_bounds__(256) k_final(
    const float* __restrict__ z2t, const float* __restrict__ W2, const float* __restrict__ b2m,
    const float* __restrict__ xrt, float* __restrict__ out) {
    __shared__ __align__(16) float zch[32][132];
    __shared__ __align__(16) float wch[32][NC];
    int b = blockIdx.y; int n0 = blockIdx.x*128; int tid = threadIdx.x;
    int nx = tid & 15, cy = tid >> 4;   // n = nx*8, c = cy*6
    float acc[8][6];
#pragma unroll
    for (int i = 0; i < 8; ++i)
#pragma unroll
        for (int j = 0; j < 6; ++j) acc[i][j] = 0.f;
    for (int kc = 0; kc < NMLP; kc += 32) {
        __syncthreads();
        for (int i = tid; i < 32*128; i += 256) {
            int kk = i >> 7, n = i & 127;
            zch[kk][n] = z2t[((size_t)b*NMLP + kc + kk)*NN + n0 + n];
        }
        for (int i = tid; i < 32*NC; i += 256) {
            int kk = i / NC, c = i % NC;
            wch[kk][c] = W2[(kc+kk)*NC + c];
        }
        __syncthreads();
        for (int kk = 0; kk < 32; ++kk) {
            f4 a0 = *(const f4*)&zch[kk][nx*8];
            f4 a1 = *(const f4*)&zch[kk][nx*8+4];
            float a[8] = {a0.x,a0.y,a0.z,a0.w,a1.x,a1.y,a1.z,a1.w};
            float2 w0 = *(const float2*)&wch[kk][cy*6];
            float2 w1 = *(const float2*)&wch[kk][cy*6+2];
            float2 w2 = *(const float2*)&wch[kk][cy*6+4];
            float bb[6] = {w0.x,w0.y,w1.x,w1.y,w2.x,w2.y};
#pragma unroll
            for (int i = 0; i < 8; ++i)
#pragma unroll
                for (int j = 0; j < 6; ++j) acc[i][j] += a[i]*bb[j];
        }
    }
#pragma unroll
    for (int j = 0; j < 6; ++j) {
        int c = cy*6 + j;
        float bias = b2m[c];
        size_t off = ((size_t)b*NC + c)*NN + n0 + nx*8;
        f4 x0 = *(const f4*)&xrt[off];
        f4 x1 = *(const f4*)&xrt[off+4];
        f4 o0 = {acc[0][j]+bias+x0.x, acc[1][j]+bias+x0.y, acc[2][j]+bias+x0.z, acc[3][j]+bias+x0.w};
        f4 o1 = {acc[4][j]+bias+x1.x, acc[5][j]+bias+x1.y, acc[6][j]+bias+x1.z, acc[7][j]+bias+x1.w};
        *(f4*)&out[off]   = o0;
        *(f4*)&out[off+4] = o1;
    }
}

// ---------------------------------------------------------------------------
extern "C" void kernel_launch(void* const* d_in, const int* in_sizes, int n_in,
                              void* d_out, int out_size, void* d_ws, size_t ws_size,
                              hipStream_t stream) {
    (void)in_sizes; (void)n_in; (void)out_size; (void)ws_size;
    const float* x     = (const float*)d_in[0];
    const float* means = (const float*)d_in[1];
    const float* ln1_g = (const float*)d_in[2];
    const float* ln1_b = (const float*)d_in[3];
    const float* Wkg   = (const float*)d_in[4];
    const float* Wvg   = (const float*)d_in[5];
    const float* Wq    = (const float*)d_in[6];
    const float* Wk    = (const float*)d_in[7];
    const float* Wv    = (const float*)d_in[8];
    const float* Wproj = (const float*)d_in[9];
    const float* Wconv = (const float*)d_in[10];
    const float* ln2_g = (const float*)d_in[11];
    const float* ln2_b = (const float*)d_in[12];
    const float* W1    = (const float*)d_in[13];
    const float* b1    = (const float*)d_in[14];
    const float* Wdw   = (const float*)d_in[15];
    const float* bdw   = (const float*)d_in[16];
    const float* W2    = (const float*)d_in[17];
    const float* b2    = (const float*)d_in[18];
    float* out = (float*)d_out;

    float* ws = (float*)d_ws;
    const size_t SZ = (size_t)NB*NN*NC;
    float* xn   = ws;
    float* qs   = ws + SZ;
    float* ks   = ws + 2*SZ;
    float* vs   = ws + 3*SZ;
    float* attn = ws + 4*SZ;
    float* xrt  = ws;          // reuse xn (dead after k_qkv)
    float* z1t  = ws + SZ;     // reuse qs,ks (dead after k_attn)
    float* z2t  = ws + 3*SZ;   // reuse vs,attn
    float* faux = ws + 5*SZ;
    float* mnn  = faux;            // 768
    float* gdot = faux + 768;      // 8
    float* bdot = faux + 776;      // 8
    float* kg   = faux + 784;      // 768
    float* vg   = faux + 1552;     // 768
    float* wpc  = faux + 2320;     // 9216 -> ends at 11536
    int* iaux   = (int*)(faux + 11536);
    int* belong = iaux;                  // NB*NN
    int* idx    = iaux + NB*NN;          // NB*NN
    int* inv    = iaux + 2*NB*NN;        // NB*NN
    int* hist   = iaux + 3*NB*NN;        // NB*128*8
    int* baseb  = hist + NB*128*NTOK;    // NB*128*8

    k_precompute<<<dim3(5), dim3(256), 0, stream>>>(
        means, ln1_g, ln1_b, Wkg, Wvg, Wproj, Wconv, mnn, gdot, bdot, kg, vg, wpc);
    k_ln1<<<dim3(NN/64, NB), dim3(256), 0, stream>>>(
        x, ln1_g, ln1_b, mnn, gdot, bdot, xn, belong);
    k_hist<<<dim3(NN/256, NB), dim3(256), 0, stream>>>(belong, hist);
    k_scan<<<dim3(NB), dim3(256), 0, stream>>>(hist, baseb);
    k_scatteridx<<<dim3(NN/256, NB), dim3(256), 0, stream>>>(belong, baseb, idx, inv);
    k_qkv<<<dim3(NN/128, NB), dim3(256), 0, stream>>>(xn, idx, Wq, Wk, Wv, qs, ks, vs);
    k_attn<<<dim3(NGRP, NHEADS, NB), dim3(256), 0, stream>>>(qs, ks, vs, kg, vg, attn);
    k_scatproj<<<dim3(NN/64, NB), dim3(256), 0, stream>>>(attn, inv, wpc, x, xrt);
    k_mlp1<<<dim3(NN/64, NB), dim3(256), 0, stream>>>(xrt, ln2_g, ln2_b, W1, b1, z1t);
    k_dwconv<<<dim3(4, NMLP, NB), dim3(256), 0, stream>>>(z1t, Wdw, bdw, z2t);
    k_final<<<dim3(NN/128, NB), dim3(256), 0, stream>>>(z2t, W2, b2, xrt, out);
}

// Round 8
// 632.661 us; speedup vs baseline: 1.2714x; 1.1039x over previous
//
#include <hip/hip_runtime.h>
#include <math.h>

#define NB 2
#define NC 96
#define ND 8
#define NHH 64
#define NWW 64
#define NN 32768          // ND*NHH*NWW
#define NTOK 8
#define NHEADS 6
#define GSZ 128
#define NGRP 256          // NN/GSZ
#define NMLP 192

typedef float4 f4;

__device__ __forceinline__ float gelu_f(float x) {
    return 0.5f * x * (1.0f + erff(x * 0.70710678118654752440f));
}

// ---------------------------------------------------------------------------
// Precompute (grid=5): blk0: normalized means, gdot/bdot, kg/vg.
// blk1..4: wpc = Wproj @ Wconv, 24 rows each, fully LDS-staged.
// ---------------------------------------------------------------------------
__global__ void __launch_bounds__(256) k_precompute(
    const float* __restrict__ means, const float* __restrict__ g1, const float* __restrict__ b1v,
    const float* __restrict__ Wkg, const float* __restrict__ Wvg,
    const float* __restrict__ Wproj, const float* __restrict__ Wconv,
    float* __restrict__ mnn, float* __restrict__ gdot, float* __restrict__ bdot,
    float* __restrict__ kg, float* __restrict__ vg, float* __restrict__ wpc) {
    int blk = blockIdx.x; int tid = threadIdx.x;
    if (blk == 0) {
        __shared__ float mlds[NTOK*NC];
        __shared__ float glds[NC], blds[NC];
        for (int i = tid; i < NTOK*NC; i += 256) mlds[i] = means[i];
        if (tid < NC) { glds[tid] = g1[tid]; blds[tid] = b1v[tid]; }
        __syncthreads();
        if (tid < NTOK) {
            float ss = 0.f;
            for (int c = 0; c < NC; ++c) { float v = mlds[tid*NC+c]; ss += v*v; }
            float inv = 1.0f / fmaxf(sqrtf(ss), 1e-12f);
            float gd = 0.f, bd = 0.f;
            for (int c = 0; c < NC; ++c) {
                float v = mlds[tid*NC+c] * inv;
                mnn[tid*NC+c] = v;
                gd += glds[c]*v; bd += blds[c]*v;
            }
            gdot[tid] = gd; bdot[tid] = bd;
        }
        // kg/vg: layout [h][t][e], e<16
        for (int i = tid; i < NHEADS*NTOK*16; i += 256) {
            int h = i / (NTOK*16); int r = i % (NTOK*16); int t = r / 16; int e = r % 16;
            float sk = 0.f, sv = 0.f;
            for (int c = 0; c < NC; ++c) {
                float mv = mlds[t*NC+c];
                sk += mv * Wkg[c*NC + h*16+e];
                sv += mv * Wvg[c*NC + h*16+e];
            }
            kg[i] = sk; vg[i] = sv;
        }
    } else {
        int r0 = (blk-1)*24;
        __shared__ float wcv[NC][NC];
        __shared__ float wpl[24][NC];
        for (int i = tid; i < NC*NC; i += 256) wcv[i/NC][i%NC] = Wconv[i];
        for (int i = tid; i < 24*NC; i += 256) wpl[i/NC][i%NC] = Wproj[(r0 + i/NC)*NC + i%NC];
        __syncthreads();
        for (int o = tid; o < 24*NC; o += 256) {
            int r = o / NC, c = o % NC;
            float s = 0.f;
            for (int k = 0; k < NC; ++k) s += wpl[r][k]*wcv[k][c];
            wpc[(r0+r)*NC + c] = s;
        }
    }
}

// ---------------------------------------------------------------------------
// LN1 (reads x in (b,c,n), writes xn in (b,n,c)) fused with cluster argmax.
// ---------------------------------------------------------------------------
__global__ void __launch_bounds__(256) k_ln1(
    const float* __restrict__ x, const float* __restrict__ g1, const float* __restrict__ b1v,
    const float* __restrict__ mnn, const float* __restrict__ gdot, const float* __restrict__ bdot,
    float* __restrict__ xn, int* __restrict__ belong) {
    __shared__ __align__(16) float xt[NC][68];
    __shared__ float meanl[64], rstdl[64];
    __shared__ float gl[NC], bl[NC], gdl[NTOK], bdl[NTOK];
    int b = blockIdx.y; int n0 = blockIdx.x * 64;
    int tid = threadIdx.x;
    if (tid < NC) { gl[tid] = g1[tid]; bl[tid] = b1v[tid]; }
    if (tid >= NC && tid < NC+NTOK) { gdl[tid-NC] = gdot[tid-NC]; bdl[tid-NC] = bdot[tid-NC]; }
    for (int i = tid; i < NC*64; i += 256) {
        int c = i >> 6, n = i & 63;
        xt[c][n] = x[((size_t)b*NC + c)*NN + n0 + n];
    }
    __syncthreads();
    int lane = tid & 63, w = tid >> 6;
    float ga = gl[lane];
    float gb = (lane < 32) ? gl[64+lane] : 0.f;
    float ma[NTOK], mb[NTOK];
#pragma unroll
    for (int t = 0; t < NTOK; ++t) {
        ma[t] = mnn[t*NC + lane];
        mb[t] = (lane < 32) ? mnn[t*NC + 64 + lane] : 0.f;
    }
    for (int tk = 0; tk < 16; ++tk) {
        int tok = w*16 + tk;
        float a  = xt[lane][tok];
        float bb = (lane < 32) ? xt[64+lane][tok] : 0.f;
        float red[10];
        red[0] = a + bb;
        red[1] = a*a + bb*bb;
        float ag = a*ga, bg = bb*gb;
#pragma unroll
        for (int t = 0; t < NTOK; ++t) red[2+t] = ag*ma[t] + bg*mb[t];
#pragma unroll
        for (int off = 32; off > 0; off >>= 1) {
#pragma unroll
            for (int r = 0; r < 10; ++r) red[r] += __shfl_xor(red[r], off);
        }
        if (lane == 0) {
            float mean = red[0] * (1.0f/NC);
            float var  = red[1] * (1.0f/NC) - mean*mean;
            float rstd = rsqrtf(var + 1e-5f);
            meanl[tok] = mean; rstdl[tok] = rstd;
            int best = 0; float bestv = -1e30f;
#pragma unroll
            for (int t = 0; t < NTOK; ++t) {
                float sc = rstd*(red[2+t] - mean*gdl[t]) + bdl[t];
                if (sc > bestv) { bestv = sc; best = t; }
            }
            belong[b*NN + n0 + tok] = best;
        }
    }
    __syncthreads();
    for (int i = tid; i < 64*NC; i += 256) {
        int n = i / NC, c = i % NC;
        float v = (xt[c][n] - meanl[n]) * rstdl[n] * gl[c] + bl[c];
        xn[((size_t)b*NN + n0 + n)*NC + c] = v;
    }
}

// ---------------------------------------------------------------------------
// Stable counting sort of `belong` (values 0..7): hist -> scan -> scatter
// ---------------------------------------------------------------------------
__global__ void __launch_bounds__(256) k_hist(const int* __restrict__ belong, int* __restrict__ hist) {
    int b = blockIdx.y, ch = blockIdx.x, tid = threadIdx.x;
    __shared__ int wc[4][NTOK];
    int myt = belong[b*NN + ch*256 + tid];
    int w = tid >> 6, lane = tid & 63;
#pragma unroll
    for (int t = 0; t < NTOK; ++t) {
        unsigned long long m = __ballot(myt == t);
        if (lane == 0) wc[w][t] = __popcll(m);
    }
    __syncthreads();
    if (tid < NTOK) hist[(b*128 + ch)*NTOK + tid] = wc[0][tid]+wc[1][tid]+wc[2][tid]+wc[3][tid];
}

__global__ void __launch_bounds__(256) k_scan(const int* __restrict__ hist, int* __restrict__ base) {
    int b = blockIdx.x, tid = threadIdx.x;
    __shared__ int A[NTOK][128], Bf[NTOK][128], orig[NTOK][128];
    __shared__ int cb[NTOK];
    for (int i = tid; i < NTOK*128; i += 256) {
        int t = i >> 7, ch = i & 127;
        int v = hist[(b*128 + ch)*NTOK + t];
        A[t][ch] = v; orig[t][ch] = v;
    }
    __syncthreads();
    for (int d = 1; d < 128; d <<= 1) {
        for (int i = tid; i < NTOK*128; i += 256) {
            int t = i >> 7, ch = i & 127;
            Bf[t][ch] = A[t][ch] + ((ch >= d) ? A[t][ch-d] : 0);
        }
        __syncthreads();
        for (int i = tid; i < NTOK*128; i += 256) {
            int t = i >> 7, ch = i & 127;
            A[t][ch] = Bf[t][ch];
        }
        __syncthreads();
    }
    if (tid == 0) {
        int run = 0;
        for (int t = 0; t < NTOK; ++t) { cb[t] = run; run += A[t][127]; }
    }
    __syncthreads();
    for (int i = tid; i < NTOK*128; i += 256) {
        int t = i >> 7, ch = i & 127;
        base[(b*128 + ch)*NTOK + t] = cb[t] + A[t][ch] - orig[t][ch];
    }
}

__global__ void __launch_bounds__(256) k_scatteridx(
    const int* __restrict__ belong, const int* __restrict__ base,
    int* __restrict__ idx, int* __restrict__ inv) {
    int b = blockIdx.y, ch = blockIdx.x, tid = threadIdx.x;
    __shared__ int wc[4][NTOK];
    __shared__ int woff[4][NTOK];
    int n = ch*256 + tid;
    int myt = belong[b*NN + n];
    int w = tid >> 6, lane = tid & 63;
    unsigned long long mymask = 0;
#pragma unroll
    for (int t = 0; t < NTOK; ++t) {
        unsigned long long m = __ballot(myt == t);
        if (myt == t) mymask = m;
        if (lane == 0) wc[w][t] = __popcll(m);
    }
    __syncthreads();
    if (tid < 32) {
        int w2 = tid >> 3, t = tid & 7;
        int s = 0;
        for (int ww = 0; ww < w2; ++ww) s += wc[ww][t];
        woff[w2][t] = s;
    }
    __syncthreads();
    int rank = __popcll(mymask & ((1ull << lane) - 1ull));
    int p = base[(b*128+ch)*NTOK + myt] + woff[w][myt] + rank;
    idx[b*NN + p] = n;
    inv[b*NN + n] = p;
}

// ---------------------------------------------------------------------------
// q/k/v = gather(xn, idx) @ {Wq,Wk,Wv}; 128-row tile, thread = 8n x 6c
// ---------------------------------------------------------------------------
__global__ void __launch_bounds__(256) k_qkv(
    const float* __restrict__ xn, const int* __restrict__ idx,
    const float* __restrict__ Wq, const float* __restrict__ Wk, const float* __restrict__ Wv,
    float* __restrict__ qs, float* __restrict__ ks, float* __restrict__ vs) {
    __shared__ __align__(16) float xnT[NC][132];
    __shared__ __align__(16) float wch[32][NC];
    __shared__ int idxl[128];
    int b = blockIdx.y; int p0 = blockIdx.x * 128; int tid = threadIdx.x;
    if (tid < 128) idxl[tid] = idx[b*NN + p0 + tid];
    __syncthreads();
    for (int i = tid; i < 128*NC; i += 256) {
        int p = i / NC, c = i % NC;
        xnT[c][p] = xn[((size_t)b*NN + idxl[p])*NC + c];
    }
    int cx = tid & 15, ny = tid >> 4;   // c = cx*6, n = ny*8
    const float* Ws[3] = {Wq, Wk, Wv};
    float* Os[3] = {qs, ks, vs};
    for (int m = 0; m < 3; ++m) {
        float acc[8][6];
#pragma unroll
        for (int i = 0; i < 8; ++i)
#pragma unroll
            for (int j = 0; j < 6; ++j) acc[i][j] = 0.f;
        const float* W = Ws[m];
        for (int kc = 0; kc < NC; kc += 32) {
            __syncthreads();
            for (int i = tid; i < 32*NC; i += 256) {
                int kk = i / NC, c = i % NC;
                wch[kk][c] = W[(kc+kk)*NC + c];
            }
            __syncthreads();
            for (int kk = 0; kk < 32; ++kk) {
                f4 a0 = *(const f4*)&xnT[kc+kk][ny*8];
                f4 a1 = *(const f4*)&xnT[kc+kk][ny*8+4];
                float a[8] = {a0.x,a0.y,a0.z,a0.w,a1.x,a1.y,a1.z,a1.w};
                float2 w0 = *(const float2*)&wch[kk][cx*6];
                float2 w1 = *(const float2*)&wch[kk][cx*6+2];
                float2 w2 = *(const float2*)&wch[kk][cx*6+4];
                float bb[6] = {w0.x,w0.y,w1.x,w1.y,w2.x,w2.y};
#pragma unroll
                for (int i = 0; i < 8; ++i)
#pragma unroll
                    for (int j = 0; j < 6; ++j) acc[i][j] += a[i]*bb[j];
            }
        }
        float* O = Os[m];
#pragma unroll
        for (int i = 0; i < 8; ++i) {
            size_t off = ((size_t)b*NN + p0 + ny*8 + i)*NC + cx*6;
            float2 s0 = {acc[i][0], acc[i][1]};
            float2 s1 = {acc[i][2], acc[i][3]};
            float2 s2 = {acc[i][4], acc[i][5]};
            *(float2*)&O[off]   = s0;
            *(float2*)&O[off+2] = s1;
            *(float2*)&O[off+4] = s2;
        }
    }
}

// ---------------------------------------------------------------------------
// Windowed attention: 4 waves/block, thread = (row, half), halves of a row
// at lanes +/-32 of the same wave -> shfl merge. Chunked-branchless online
// softmax (8 keys/chunk). Scale folded into q. NOTE: no min-waves hint --
// the (256,4) variant capped VGPR at 64 and spilled ~240 MB to scratch.
// ---------------------------------------------------------------------------
__global__ void __launch_bounds__(256) k_attn(
    const float* __restrict__ qs, const float* __restrict__ ks, const float* __restrict__ vs,
    const float* __restrict__ kg, const float* __restrict__ vg,
    float* __restrict__ attn) {
    __shared__ __align__(16) f4 kt[256][4];
    __shared__ __align__(16) f4 vt[256][4];
    __shared__ __align__(16) f4 kgs[NTOK][4];
    __shared__ __align__(16) f4 vgs[NTOK][4];
    int g = blockIdx.x, h = blockIdx.y, b = blockIdx.z;
    int tid = threadIdx.x;
    for (int i = tid; i < 1024; i += 256) {
        int r = i >> 2, c = i & 3;
        int src = g*GSZ + r;
        if (g == NGRP-1 && r >= GSZ) src = NN - 1 - (r - GSZ);
        size_t off = ((size_t)b*NN + src)*NC + h*16 + c*4;
        kt[r][c] = *(const f4*)&ks[off];
        vt[r][c] = *(const f4*)&vs[off];
    }
    if (tid < 32) {
        int t = tid >> 2, c = tid & 3;
        kgs[t][c] = *(const f4*)&kg[(h*NTOK + t)*16 + c*4];
        vgs[t][c] = *(const f4*)&vg[(h*NTOK + t)*16 + c*4];
    }
    int wv = tid >> 6, lane = tid & 63;
    int row = wv*32 + (lane & 31);
    int half = lane >> 5;
    float qv[16];
    {
        const f4* qp = (const f4*)&qs[((size_t)b*NN + g*GSZ + row)*NC + h*16];
#pragma unroll
        for (int i = 0; i < 4; ++i) {
            f4 t = qp[i];
            qv[i*4+0]=t.x*0.25f; qv[i*4+1]=t.y*0.25f; qv[i*4+2]=t.z*0.25f; qv[i*4+3]=t.w*0.25f;
        }
    }
    __syncthreads();
    float m = -1e30f, l = 0.f;
    float acc[16];
#pragma unroll
    for (int e = 0; e < 16; ++e) acc[e] = 0.f;
    int k0 = half * GSZ;
    for (int c8 = 0; c8 < 16; ++c8) {
        float s[8];
#pragma unroll
        for (int j = 0; j < 8; ++j) {
            const f4* kp = &kt[k0 + c8*8 + j][0];
            f4 ka = kp[0], kb = kp[1], kc = kp[2], kd = kp[3];
            s[j] = qv[0]*ka.x + qv[1]*ka.y + qv[2]*ka.z + qv[3]*ka.w
                 + qv[4]*kb.x + qv[5]*kb.y + qv[6]*kb.z + qv[7]*kb.w
                 + qv[8]*kc.x + qv[9]*kc.y + qv[10]*kc.z + qv[11]*kc.w
                 + qv[12]*kd.x + qv[13]*kd.y + qv[14]*kd.z + qv[15]*kd.w;
        }
        float cm = fmaxf(fmaxf(fmaxf(s[0],s[1]), fmaxf(s[2],s[3])),
                         fmaxf(fmaxf(s[4],s[5]), fmaxf(s[6],s[7])));
        float nm = fmaxf(m, cm);
        float corr = __expf(m - nm);
        m = nm;
        l *= corr;
#pragma unroll
        for (int e = 0; e < 16; ++e) acc[e] *= corr;
#pragma unroll
        for (int j = 0; j < 8; ++j) {
            float p = __expf(s[j] - m);
            l += p;
            const f4* vp = &vt[k0 + c8*8 + j][0];
            f4 va = vp[0], vb = vp[1], vc = vp[2], vd = vp[3];
            acc[0] += p*va.x; acc[1] += p*va.y; acc[2] += p*va.z; acc[3] += p*va.w;
            acc[4] += p*vb.x; acc[5] += p*vb.y; acc[6] += p*vb.z; acc[7] += p*vb.w;
            acc[8] += p*vc.x; acc[9] += p*vc.y; acc[10] += p*vc.z; acc[11] += p*vc.w;
            acc[12] += p*vd.x; acc[13] += p*vd.y; acc[14] += p*vd.z; acc[15] += p*vd.w;
        }
    }
    // global attention over 8 cluster tokens (redundant in both halves: no divergence)
    float m2 = -1e30f, l2 = 0.f;
    float a2[16];
#pragma unroll
    for (int e = 0; e < 16; ++e) a2[e] = 0.f;
#pragma unroll
    for (int t = 0; t < NTOK; ++t) {
        f4 ka = kgs[t][0], kb = kgs[t][1], kc = kgs[t][2], kd = kgs[t][3];
        float s = qv[0]*ka.x + qv[1]*ka.y + qv[2]*ka.z + qv[3]*ka.w
                + qv[4]*kb.x + qv[5]*kb.y + qv[6]*kb.z + qv[7]*kb.w
                + qv[8]*kc.x + qv[9]*kc.y + qv[10]*kc.z + qv[11]*kc.w
                + qv[12]*kd.x + qv[13]*kd.y + qv[14]*kd.z + qv[15]*kd.w;
        float nm2 = fmaxf(m2, s);
        float corr = __expf(m2 - nm2);
        m2 = nm2;
        l2 *= corr;
        float p = __expf(s - m2);
        l2 += p;
        f4 va = vgs[t][0], vb = vgs[t][1], vc = vgs[t][2], vd = vgs[t][3];
#pragma unroll
        for (int e = 0; e < 16; ++e) a2[e] *= corr;
        a2[0] += p*va.x; a2[1] += p*va.y; a2[2] += p*va.z; a2[3] += p*va.w;
        a2[4] += p*vb.x; a2[5] += p*vb.y; a2[6] += p*vb.z; a2[7] += p*vb.w;
        a2[8] += p*vc.x; a2[9] += p*vc.y; a2[10] += p*vc.z; a2[11] += p*vc.w;
        a2[12] += p*vd.x; a2[13] += p*vd.y; a2[14] += p*vd.z; a2[15] += p*vd.w;
    }
    float inv2 = 1.f / l2;
    // merge halves via shfl across lane ^ 32
    float om = __shfl_xor(m, 32);
    float ol = __shfl_xor(l, 32);
    float mw = fmaxf(m, om);
    float es = __expf(m - mw), eo = __expf(om - mw);
    float lw = l*es + ol*eo;
    float invw = 1.f / lw;
    float o[16];
#pragma unroll
    for (int e = 0; e < 16; ++e) {
        float oa = __shfl_xor(acc[e], 32);
        o[e] = (acc[e]*es + oa*eo)*invw + a2[e]*inv2;
    }
    if (half == 0) {
        f4* op = (f4*)&attn[((size_t)b*NN + g*GSZ + row)*NC + h*16];
#pragma unroll
        for (int i = 0; i < 4; ++i) {
            f4 t = {o[i*4+0], o[i*4+1], o[i*4+2], o[i*4+3]};
            op[i] = t;
        }
    }
}

// ---------------------------------------------------------------------------
// Scatter back (inv), @ (Wproj@Wconv), + residual x; writes xrt in (b,c,n)
// ---------------------------------------------------------------------------
__global__ void __launch_bounds__(256) k_scatproj(
    const float* __restrict__ attn, const int* __restrict__ inv,
    const float* __restrict__ wpc, const float* __restrict__ x,
    float* __restrict__ xrt) {
    __shared__ __align__(16) float attT[NC][68];
    __shared__ __align__(16) float wch[32][NC];
    __shared__ int invl[64];
    int b = blockIdx.y; int n0 = blockIdx.x * 64; int tid = threadIdx.x;
    if (tid < 64) invl[tid] = inv[b*NN + n0 + tid];
    __syncthreads();
    for (int i = tid; i < 64*NC; i += 256) {
        int n = i / NC, c = i % NC;
        attT[c][n] = attn[((size_t)b*NN + invl[n])*NC + c];
    }
    int nx = tid & 15, cy = tid >> 4;  // n = nx*4, c = cy*6
    float acc[4][6];
#pragma unroll
    for (int i = 0; i < 4; ++i)
#pragma unroll
        for (int j = 0; j < 6; ++j) acc[i][j] = 0.f;
    for (int kc = 0; kc < NC; kc += 32) {
        __syncthreads();
        for (int i = tid; i < 32*NC; i += 256) {
            int kk = i / NC, c = i % NC;
            wch[kk][c] = wpc[(kc+kk)*NC + c];
        }
        __syncthreads();
        for (int kk = 0; kk < 32; ++kk) {
            f4 a0 = *(const f4*)&attT[kc+kk][nx*4];
            float a[4] = {a0.x,a0.y,a0.z,a0.w};
            float2 w0 = *(const float2*)&wch[kk][cy*6];
            float2 w1 = *(const float2*)&wch[kk][cy*6+2];
            float2 w2 = *(const float2*)&wch[kk][cy*6+4];
            float bb[6] = {w0.x,w0.y,w1.x,w1.y,w2.x,w2.y};
#pragma unroll
            for (int i = 0; i < 4; ++i)
#pragma unroll
                for (int j = 0; j < 6; ++j) acc[i][j] += a[i]*bb[j];
        }
    }
#pragma unroll
    for (int j = 0; j < 6; ++j) {
        int c = cy*6 + j;
        size_t off = ((size_t)b*NC + c)*NN + n0 + nx*4;
        f4 xv = *(const f4*)&x[off];
        f4 o = {acc[0][j]+xv.x, acc[1][j]+xv.y, acc[2][j]+xv.z, acc[3][j]+xv.w};
        *(f4*)&xrt[off] = o;
    }
}

// ---------------------------------------------------------------------------
// LN2 + @W1 + b1 + GELU; reads xrt (b,c,n), writes z1t (b, m, n)
// ---------------------------------------------------------------------------
__global__ void __launch_bounds__(256) k_mlp1(
    const float* __restrict__ xrt, const float* __restrict__ g2, const float* __restrict__ b2v,
    const float* __restrict__ W1, const float* __restrict__ b1m,
    float* __restrict__ z1t) {
    __shared__ __align__(16) float xt[NC][68];
    __shared__ __align__(16) float wch[32][NMLP];
    __shared__ float meanl[64], rstdl[64];
    __shared__ float gl[NC], bl[NC];
    int b = blockIdx.y; int n0 = blockIdx.x*64; int tid = threadIdx.x;
    if (tid < NC) { gl[tid] = g2[tid]; bl[tid] = b2v[tid]; }
    for (int i = tid; i < NC*64; i += 256) {
        int c = i >> 6, n = i & 63;
        xt[c][n] = xrt[((size_t)b*NC + c)*NN + n0 + n];
    }
    __syncthreads();
    int lane = tid & 63, w = tid >> 6;
    for (int tk = 0; tk < 16; ++tk) {
        int tok = w*16 + tk;
        float a  = xt[lane][tok];
        float bb = (lane < 32) ? xt[64+lane][tok] : 0.f;
        float s = a + bb, sq = a*a + bb*bb;
#pragma unroll
        for (int off = 32; off > 0; off >>= 1) {
            s  += __shfl_xor(s, off);
            sq += __shfl_xor(sq, off);
        }
        if (lane == 0) {
            float mean = s * (1.0f/NC);
            float var  = sq * (1.0f/NC) - mean*mean;
            meanl[tok] = mean; rstdl[tok] = rsqrtf(var + 1e-5f);
        }
    }
    __syncthreads();
    for (int i = tid; i < NC*64; i += 256) {
        int c = i >> 6, n = i & 63;
        xt[c][n] = (xt[c][n]-meanl[n])*rstdl[n]*gl[c]+bl[c];
    }
    int nx = tid & 15, my = tid >> 4;  // n = nx*4, m = my*12
    float acc[4][12];
#pragma unroll
    for (int i = 0; i < 4; ++i)
#pragma unroll
        for (int j = 0; j < 12; ++j) acc[i][j] = 0.f;
    for (int kc = 0; kc < NC; kc += 32) {
        __syncthreads();
        for (int i = tid; i < 32*NMLP; i += 256) {
            int kk = i / NMLP, c = i % NMLP;
            wch[kk][c] = W1[(kc+kk)*NMLP + c];
        }
        __syncthreads();
        for (int kk = 0; kk < 32; ++kk) {
            f4 a0 = *(const f4*)&xt[kc+kk][nx*4];
            float a[4] = {a0.x,a0.y,a0.z,a0.w};
            f4 w0 = *(const f4*)&wch[kk][my*12];
            f4 w1 = *(const f4*)&wch[kk][my*12+4];
            f4 w2 = *(const f4*)&wch[kk][my*12+8];
            float bb[12] = {w0.x,w0.y,w0.z,w0.w,w1.x,w1.y,w1.z,w1.w,w2.x,w2.y,w2.z,w2.w};
#pragma unroll
            for (int i = 0; i < 4; ++i)
#pragma unroll
                for (int j = 0; j < 12; ++j) acc[i][j] += a[i]*bb[j];
        }
    }
#pragma unroll
    for (int j = 0; j < 12; ++j) {
        int mm = my*12 + j;
        float bias = b1m[mm];
        size_t off = ((size_t)b*NMLP + mm)*NN + n0 + nx*4;
        f4 o = { gelu_f(acc[0][j]+bias), gelu_f(acc[1][j]+bias),
                 gelu_f(acc[2][j]+bias), gelu_f(acc[3][j]+bias) };
        *(f4*)&z1t[off] = o;
    }
}

// ---------------------------------------------------------------------------
// Depthwise 5x5x5 conv (pad 2) + GELU + add z1; z2t (b,m,n), register-blocked
// ---------------------------------------------------------------------------
__global__ void __launch_bounds__(256) k_dwconv(
    const float* __restrict__ z1t, const float* __restrict__ Wdw, const float* __restrict__ bdw,
    float* __restrict__ z2t) {
    __shared__ __align__(16) float tin[ND][20][72];
    __shared__ float wl[128];
    int ht = blockIdx.x, mch = blockIdx.y, b = blockIdx.z;
    int h0 = ht*16; int tid = threadIdx.x;
    if (tid < 125) wl[tid] = Wdw[mch*125 + tid];
    const float* src = &z1t[((size_t)b*NMLP + mch)*NN];
    for (int i = tid; i < ND*20*68; i += 256) {
        int dd = i / (20*68); int r = i % (20*68); int hh = r / 68; int ww = r % 68;
        int gh = h0 + hh - 2, gw = ww - 2;
        float v = 0.f;
        if ((unsigned)gh < 64u && (unsigned)gw < 64u) v = src[dd*4096 + gh*64 + gw];
        tin[dd][hh][ww] = v;
    }
    __syncthreads();
    int rowid = tid >> 1; int od = rowid >> 4; int ohl = rowid & 15; int wb = (tid & 1)*32;
    float acc[32];
#pragma unroll
    for (int o = 0; o < 32; ++o) acc[o] = 0.f;
    for (int kd = 0; kd < 5; ++kd) {
        int id = od + kd - 2;
        if ((unsigned)id >= (unsigned)ND) continue;
#pragma unroll
        for (int kh = 0; kh < 5; ++kh) {
            const float* rp = &tin[id][ohl+kh][wb];
            float seg[36];
#pragma unroll
            for (int i = 0; i < 9; ++i) *(f4*)&seg[i*4] = *(const f4*)&rp[i*4];
#pragma unroll
            for (int kw = 0; kw < 5; ++kw) {
                float wt = wl[kd*25 + kh*5 + kw];
#pragma unroll
                for (int o = 0; o < 32; ++o) acc[o] += seg[o+kw]*wt;
            }
        }
    }
    float bias = bdw[mch];
    float* dst = &z2t[((size_t)b*NMLP + mch)*NN + od*4096 + (size_t)(h0+ohl)*64 + wb];
    const float* ctr = &tin[od][ohl+2][wb+2];
#pragma unroll
    for (int o4 = 0; o4 < 32; o4 += 4) {
        f4 ov = { ctr[o4+0] + gelu_f(acc[o4+0]+bias),
                  ctr[o4+1] + gelu_f(acc[o4+1]+bias),
                  ctr[o4+2] + gelu_f(acc[o4+2]+bias),
                  ctr[o4+3] + gelu_f(acc[o4+3]+bias) };
        *(f4*)&dst[o4] = ov;
    }
}

// ---------------------------------------------------------------------------
// Final: out(b,c,n) = z2 @ W2 + b2 + xrt ; 128-token tile, thread = 8n x 6c
// ---------------------------------------------------------------------------
__global__ void __launch_bounds__(256) k_final(
    const float* __restrict__ z2t, const float* __restrict__ W2, const float* __restrict__ b2m,
    const float* __restrict__ xrt, float* __restrict__ out) {
    __shared__ __align__(16) float zch[32][132];
    __shared__ __align__(16) float wch[32][NC];
    int b = blockIdx.y; int n0 = blockIdx.x*128; int tid = threadIdx.x;
    int nx = tid & 15, cy = tid >> 4;   // n = nx*8, c = cy*6
    float acc[8][6];
#pragma unroll
    for (int i = 0; i < 8; ++i)
#pragma unroll
        for (int j = 0; j < 6; ++j) acc[i][j] = 0.f;
    for (int kc = 0; kc < NMLP; kc += 32) {
        __syncthreads();
        for (int i = tid; i < 32*128; i += 256) {
            int kk = i >> 7, n = i & 127;
            zch[kk][n] = z2t[((size_t)b*NMLP + kc + kk)*NN + n0 + n];
        }
        for (int i = tid; i < 32*NC; i += 256) {
            int kk = i / NC, c = i % NC;
            wch[kk][c] = W2[(kc+kk)*NC + c];
        }
        __syncthreads();
        for (int kk = 0; kk < 32; ++kk) {
            f4 a0 = *(const f4*)&zch[kk][nx*8];
            f4 a1 = *(const f4*)&zch[kk][nx*8+4];
            float a[8] = {a0.x,a0.y,a0.z,a0.w,a1.x,a1.y,a1.z,a1.w};
            float2 w0 = *(const float2*)&wch[kk][cy*6];
            float2 w1 = *(const float2*)&wch[kk][cy*6+2];
            float2 w2 = *(const float2*)&wch[kk][cy*6+4];
            float bb[6] = {w0.x,w0.y,w1.x,w1.y,w2.x,w2.y};
#pragma unroll
            for (int i = 0; i < 8; ++i)
#pragma unroll
                for (int j = 0; j < 6; ++j) acc[i][j] += a[i]*bb[j];
        }
    }
#pragma unroll
    for (int j = 0; j < 6; ++j) {
        int c = cy*6 + j;
        float bias = b2m[c];
        size_t off = ((size_t)b*NC + c)*NN + n0 + nx*8;
        f4 x0 = *(const f4*)&xrt[off];
        f4 x1 = *(const f4*)&xrt[off+4];
        f4 o0 = {acc[0][j]+bias+x0.x, acc[1][j]+bias+x0.y, acc[2][j]+bias+x0.z, acc[3][j]+bias+x0.w};
        f4 o1 = {acc[4][j]+bias+x1.x, acc[5][j]+bias+x1.y, acc[6][j]+bias+x1.z, acc[7][j]+bias+x1.w};
        *(f4*)&out[off]   = o0;
        *(f4*)&out[off+4] = o1;
    }
}

// ---------------------------------------------------------------------------
extern "C" void kernel_launch(void* const* d_in, const int* in_sizes, int n_in,
                              void* d_out, int out_size, void* d_ws, size_t ws_size,
                              hipStream_t stream) {
    (void)in_sizes; (void)n_in; (void)out_size; (void)ws_size;
    const float* x     = (const float*)d_in[0];
    const float* means = (const float*)d_in[1];
    const float* ln1_g = (const float*)d_in[2];
    const float* ln1_b = (const float*)d_in[3];
    const float* Wkg   = (const float*)d_in[4];
    const float* Wvg   = (const float*)d_in[5];
    const float* Wq    = (const float*)d_in[6];
    const float* Wk    = (const float*)d_in[7];
    const float* Wv    = (const float*)d_in[8];
    const float* Wproj = (const float*)d_in[9];
    const float* Wconv = (const float*)d_in[10];
    const float* ln2_g = (const float*)d_in[11];
    const float* ln2_b = (const float*)d_in[12];
    const float* W1    = (const float*)d_in[13];
    const float* b1    = (const float*)d_in[14];
    const float* Wdw   = (const float*)d_in[15];
    const float* bdw   = (const float*)d_in[16];
    const float* W2    = (const float*)d_in[17];
    const float* b2    = (const float*)d_in[18];
    float* out = (float*)d_out;

    float* ws = (float*)d_ws;
    const size_t SZ = (size_t)NB*NN*NC;
    float* xn   = ws;
    float* qs   = ws + SZ;
    float* ks   = ws + 2*SZ;
    float* vs   = ws + 3*SZ;
    float* attn = ws + 4*SZ;
    float* xrt  = ws;          // reuse xn (dead after k_qkv)
    float* z1t  = ws + SZ;     // reuse qs,ks (dead after k_attn)
    float* z2t  = ws + 3*SZ;   // reuse vs,attn
    float* faux = ws + 5*SZ;
    float* mnn  = faux;            // 768
    float* gdot = faux + 768;      // 8
    float* bdot = faux + 776;      // 8
    float* kg   = faux + 784;      // 768
    float* vg   = faux + 1552;     // 768
    float* wpc  = faux + 2320;     // 9216 -> ends at 11536
    int* iaux   = (int*)(faux + 11536);
    int* belong = iaux;                  // NB*NN
    int* idx    = iaux + NB*NN;          // NB*NN
    int* inv    = iaux + 2*NB*NN;        // NB*NN
    int* hist   = iaux + 3*NB*NN;        // NB*128*8
    int* baseb  = hist + NB*128*NTOK;    // NB*128*8

    k_precompute<<<dim3(5), dim3(256), 0, stream>>>(
        means, ln1_g, ln1_b, Wkg, Wvg, Wproj, Wconv, mnn, gdot, bdot, kg, vg, wpc);
    k_ln1<<<dim3(NN/64, NB), dim3(256), 0, stream>>>(
        x, ln1_g, ln1_b, mnn, gdot, bdot, xn, belong);
    k_hist<<<dim3(NN/256, NB), dim3(256), 0, stream>>>(belong, hist);
    k_scan<<<dim3(NB), dim3(256), 0, stream>>>(hist, baseb);
    k_scatteridx<<<dim3(NN/256, NB), dim3(256), 0, stream>>>(belong, baseb, idx, inv);
    k_qkv<<<dim3(NN/128, NB), dim3(256), 0, stream>>>(xn, idx, Wq, Wk, Wv, qs, ks, vs);
    k_attn<<<dim3(NGRP, NHEADS, NB), dim3(256), 0, stream>>>(qs, ks, vs, kg, vg, attn);
    k_scatproj<<<dim3(NN/64, NB), dim3(256), 0, stream>>>(attn, inv, wpc, x, xrt);
    k_mlp1<<<dim3(NN/64, NB), dim3(256), 0, stream>>>(xrt, ln2_g, ln2_b, W1, b1, z1t);
    k_dwconv<<<dim3(4, NMLP, NB), dim3(256), 0, stream>>>(z1t, Wdw, bdw, z2t);
    k_final<<<dim3(NN/128, NB), dim3(256), 0, stream>>>(z2t, W2, b2, xrt, out);
}